// Round 8
// baseline (2170.971 us; speedup 1.0000x reference)
//
#include <hip/hip_runtime.h>
#include <hip/hip_fp16.h>
#include <math.h>

#define SCAN_BLK 256
#define BSH 13                 // bucket width = 8192 CSR slots
#define BW  (1 << BSH)

__device__ __forceinline__ float2 H2F(unsigned u) {
    __half2 h = *reinterpret_cast<__half2*>(&u);
    return __half22float2(h);
}
__device__ __forceinline__ unsigned F2H(float a, float b) {
    __half2 h = __floats2half2_rn(a, b);
    return *reinterpret_cast<unsigned*>(&h);
}

// unpack 8 fp16 edge attrs
__device__ __forceinline__ void loadA(const __half* p, float* a) {
    uint4 u = *(const uint4*)p;
    float2 t;
    t = H2F(u.x); a[0] = t.x; a[1] = t.y;
    t = H2F(u.y); a[2] = t.x; a[3] = t.y;
    t = H2F(u.z); a[4] = t.x; a[5] = t.y;
    t = H2F(u.w); a[6] = t.x; a[7] = t.y;
}

// packed per-head K/V fp16 packet
template<int C>
__device__ __forceinline__ void loadKV(const __half* p, float* k, float* v) {
    if constexpr (C == 6) {
        uint4 p0 = *(const uint4*)p;
        uint4 p1 = *(const uint4*)(p + 8);
        float2 t;
        t = H2F(p0.x); k[0] = t.x; k[1] = t.y;
        t = H2F(p0.y); k[2] = t.x; k[3] = t.y;
        t = H2F(p0.z); k[4] = t.x; k[5] = t.y;
        t = H2F(p0.w); v[0] = t.x; v[1] = t.y;
        t = H2F(p1.x); v[2] = t.x; v[3] = t.y;
        t = H2F(p1.y); v[4] = t.x; v[5] = t.y;
    } else {  // C == 3: [k0,k1,k2,v0,v1,v2,p,p]
        uint4 p0 = *(const uint4*)p;
        float2 t;
        t = H2F(p0.x); k[0] = t.x; k[1] = t.y;
        t = H2F(p0.y); k[2] = t.x; v[0] = t.y;
        t = H2F(p0.z); v[1] = t.x; v[2] = t.y;
    }
}

// ---------------- CSR build ----------------
__global__ void count_kernel(const int* __restrict__ ei, int* __restrict__ deg, int E) {
    int e = blockIdx.x * blockDim.x + threadIdx.x;
    if (e < E) atomicAdd(&deg[ei[E + e]], 1);
}

__global__ void scan1_kernel(const int* __restrict__ deg, int* __restrict__ part,
                             int* __restrict__ bsum, int N) {
    __shared__ int sm[SCAN_BLK];
    int i = blockIdx.x * SCAN_BLK + threadIdx.x;
    int v = (i < N) ? deg[i] : 0;
    sm[threadIdx.x] = v;
    __syncthreads();
    for (int off = 1; off < SCAN_BLK; off <<= 1) {
        int t = (threadIdx.x >= off) ? sm[threadIdx.x - off] : 0;
        __syncthreads();
        sm[threadIdx.x] += t;
        __syncthreads();
    }
    if (i < N) part[i] = sm[threadIdx.x] - v;
    if (threadIdx.x == SCAN_BLK - 1) bsum[blockIdx.x] = sm[threadIdx.x];
}

__global__ void scan2_kernel(const int* __restrict__ bsum, int* __restrict__ boff, int nb) {
    __shared__ int sm[512];
    int v = (threadIdx.x < nb) ? bsum[threadIdx.x] : 0;
    sm[threadIdx.x] = v;
    __syncthreads();
    for (int off = 1; off < 512; off <<= 1) {
        int t = (threadIdx.x >= off) ? sm[threadIdx.x - off] : 0;
        __syncthreads();
        sm[threadIdx.x] += t;
        __syncthreads();
    }
    if (threadIdx.x < nb) boff[threadIdx.x] = sm[threadIdx.x] - v;
}

__global__ void scan3_kernel(int* __restrict__ rowptr, const int* __restrict__ boff,
                             int N, int E) {
    int i = blockIdx.x * blockDim.x + threadIdx.x;
    if (i < N) rowptr[i] += boff[i / SCAN_BLK];
    if (i == 0) rowptr[N] = E;
}

// pass A: compute CSR slot, append (idx, e) to bucket idx>>BSH.
// idx is a permutation of [0,E) => bucket b receives exactly its range width.
__global__ void bucketA_kernel(const int* __restrict__ ei, const int* __restrict__ rowptr,
                               int* __restrict__ cursor, int* __restrict__ bcur,
                               int2* __restrict__ buck, int E) {
    int e = blockIdx.x * blockDim.x + threadIdx.x;
    if (e >= E) return;
    int dst = ei[E + e];
    int pos = atomicAdd(&cursor[dst], 1);
    int idx = rowptr[dst] + pos;
    int b = idx >> BSH;
    int t = atomicAdd(&bcur[b], 1);
    buck[((size_t)b << BSH) + t] = make_int2(idx, e);
}

// pass B: replay bucket records; writes confined to a 32KB window (L2-hot)
__global__ void bucketB_kernel(const int2* __restrict__ buck, int* __restrict__ srcp, int E) {
    int b = blockIdx.x;
    int base = b << BSH;
    int cnt = min(BW, E - base);
    for (int i = threadIdx.x; i < cnt; i += blockDim.x) {
        int2 r = buck[base + i];
        srcp[r.x] = r.y;
    }
}

// gather-permute + fp32->fp16 cvt: sequential writes; random 32B ea reads (L3).
// srcp[j]: eid -> src (in-place)
__global__ void permuteE_kernel(const int* __restrict__ ei, const float* __restrict__ ea,
                                int* __restrict__ srcp, __half* __restrict__ eap, int E) {
    int j = blockIdx.x * blockDim.x + threadIdx.x;
    if (j >= E) return;
    int e = srcp[j];
    float4 a0 = *(const float4*)(ea + (size_t)e * 8);
    float4 a1 = *(const float4*)(ea + (size_t)e * 8 + 4);
    uint4 u;
    u.x = F2H(a0.x, a0.y);
    u.y = F2H(a0.z, a0.w);
    u.z = F2H(a1.x, a1.y);
    u.w = F2H(a1.z, a1.w);
    *(uint4*)(eap + (size_t)j * 8) = u;
    srcp[j] = ei[e];
}

// ------- projections, H=8 layers: Q,S fp32 unpadded; KV fp16 packed -------
template<int CIN, int C, int PK>
__global__ void proj8_kernel(const float* __restrict__ X,
                             const float* __restrict__ wq, const float* __restrict__ bq,
                             const float* __restrict__ wk, const float* __restrict__ bk,
                             const float* __restrict__ wv, const float* __restrict__ bv,
                             const float* __restrict__ wsk, const float* __restrict__ bsk,
                             float* __restrict__ Q, __half* __restrict__ KV,
                             float* __restrict__ S, int N)
{
    const int HC = 8 * C;
    int idx = blockIdx.x * blockDim.x + threadIdx.x;
    if (idx >= N * HC) return;
    int n = idx / HC;
    int c = idx - n * HC;
    int h = c / C;
    int cc = c - h * C;
    float q = bq[c], k = bk[c], v = bv[c], s = bsk[c];
    const float* xr = X + (size_t)n * CIN;
#pragma unroll
    for (int i = 0; i < CIN; ++i) {
        float xi = xr[i];
        q = fmaf(xi, wq[i * HC + c], q);
        k = fmaf(xi, wk[i * HC + c], k);
        v = fmaf(xi, wv[i * HC + c], v);
        s = fmaf(xi, wsk[i * HC + c], s);
    }
    Q[(size_t)n * HC + c] = q;
    __half* kp = KV + (size_t)n * (8 * PK) + h * PK;
    kp[cc] = __float2half_rn(k);
    kp[C + cc] = __float2half_rn(v);
    S[(size_t)n * HC + c] = s;
}

// ------- projection, layer3: Q,S fp32; K,V fp16 rows of 64 -------
__global__ void proj64_kernel(const float* __restrict__ X,
                              const float* __restrict__ wq, const float* __restrict__ bq,
                              const float* __restrict__ wk, const float* __restrict__ bk,
                              const float* __restrict__ wv, const float* __restrict__ bv,
                              const float* __restrict__ wsk, const float* __restrict__ bsk,
                              float* __restrict__ Q, __half* __restrict__ K16,
                              __half* __restrict__ V16, float* __restrict__ S, int N)
{
    int idx = blockIdx.x * blockDim.x + threadIdx.x;
    if (idx >= N * 64) return;
    int n = idx >> 6;
    int c = idx & 63;
    float q = bq[c], k = bk[c], v = bv[c], s = bsk[c];
    const float* xr = X + (size_t)n * 24;
#pragma unroll
    for (int i = 0; i < 24; ++i) {
        float xi = xr[i];
        q = fmaf(xi, wq[i * 64 + c], q);
        k = fmaf(xi, wk[i * 64 + c], k);
        v = fmaf(xi, wv[i * 64 + c], v);
        s = fmaf(xi, wsk[i * 64 + c], s);
    }
    Q[idx] = q;
    K16[idx] = __float2half_rn(k);
    V16[idx] = __float2half_rn(v);
    S[idx] = s;
}

// ---- fused gather+gate, H=8: thread per (node, head), factorized e -----
template<int C, int PK>
__global__ void gather8f_kernel(const int* __restrict__ rowptr,
                                const int* __restrict__ srcp,
                                const __half* __restrict__ eap,
                                const float* __restrict__ we,
                                const float* __restrict__ Q,
                                const __half* __restrict__ KV,
                                const float* __restrict__ S,
                                const float* __restrict__ wb,
                                float* __restrict__ OUT,
                                int N, float scale)
{
    const int HC = 8 * C;
    int tid = blockIdx.x * blockDim.x + threadIdx.x;
    int n = tid >> 3;
    int h = tid & 7;
    if (n >= N) return;

    float q[C];
    const float* Qp = Q + (size_t)n * HC + h * C;
#pragma unroll
    for (int c = 0; c < C; ++c) q[c] = Qp[c];

    float qe[8];
#pragma unroll
    for (int d = 0; d < 8; ++d) {
        float t = 0.f;
#pragma unroll
        for (int c = 0; c < C; ++c) t = fmaf(we[d * HC + h * C + c], q[c], t);
        qe[d] = t;
    }

    float num[C];
#pragma unroll
    for (int c = 0; c < C; ++c) num[c] = 0.f;
    float sacc[8];
#pragma unroll
    for (int d = 0; d < 8; ++d) sacc[d] = 0.f;
    float den = 0.f;

    int rs = rowptr[n], re = rowptr[n + 1];
    int j = rs;
    for (; j + 1 < re; j += 2) {
        int s0 = srcp[j], s1 = srcp[j + 1];
        float a0[8], a1[8];
        loadA(eap + (size_t)j * 8, a0);
        loadA(eap + (size_t)(j + 1) * 8, a1);
        float k0[C], v0[C], k1[C], v1[C];
        loadKV<C>(KV + (size_t)s0 * (8 * PK) + h * PK, k0, v0);
        loadKV<C>(KV + (size_t)s1 * (8 * PK) + h * PK, k1, v1);
        float d0 = 0.f, d1 = 0.f;
#pragma unroll
        for (int c = 0; c < C; ++c) {
            d0 = fmaf(q[c], k0[c], d0);
            d1 = fmaf(q[c], k1[c], d1);
        }
        float qa0 = 0.f, qa1 = 0.f;
#pragma unroll
        for (int d = 0; d < 8; ++d) {
            qa0 = fmaf(qe[d], a0[d], qa0);
            qa1 = fmaf(qe[d], a1[d], qa1);
        }
        float ex0 = __expf((d0 + qa0) * scale);
        float ex1 = __expf((d1 + qa1) * scale);
        den += ex0 + ex1;
#pragma unroll
        for (int c = 0; c < C; ++c) {
            num[c] = fmaf(ex0, v0[c], num[c]);
            num[c] = fmaf(ex1, v1[c], num[c]);
        }
#pragma unroll
        for (int d = 0; d < 8; ++d)
            sacc[d] = fmaf(ex0, a0[d], fmaf(ex1, a1[d], sacc[d]));
    }
    if (j < re) {
        int s0 = srcp[j];
        float a0[8];
        loadA(eap + (size_t)j * 8, a0);
        float k0[C], v0[C];
        loadKV<C>(KV + (size_t)s0 * (8 * PK) + h * PK, k0, v0);
        float d0 = 0.f;
#pragma unroll
        for (int c = 0; c < C; ++c) d0 = fmaf(q[c], k0[c], d0);
        float qa0 = 0.f;
#pragma unroll
        for (int d = 0; d < 8; ++d) qa0 = fmaf(qe[d], a0[d], qa0);
        float ex0 = __expf((d0 + qa0) * scale);
        den += ex0;
#pragma unroll
        for (int c = 0; c < C; ++c) num[c] = fmaf(ex0, v0[c], num[c]);
#pragma unroll
        for (int d = 0; d < 8; ++d) sacc[d] = fmaf(ex0, a0[d], sacc[d]);
    }

    float inv = 1.f / (den + 1e-16f);
    float outc[C], sc[C];
    float gd = 0.f;
#pragma unroll
    for (int c = 0; c < C; ++c) {
        float e_ = 0.f;
#pragma unroll
        for (int d = 0; d < 8; ++d) e_ = fmaf(we[d * HC + h * C + c], sacc[d], e_);
        float o = (num[c] + e_) * inv;
        float s_ = S[(size_t)n * HC + h * C + c];
        outc[c] = o;
        sc[c] = s_;
        gd += o * wb[h * C + c] + s_ * wb[HC + h * C + c] + (o - s_) * wb[2 * HC + h * C + c];
    }
    gd += __shfl_xor(gd, 1, 8);
    gd += __shfl_xor(gd, 2, 8);
    gd += __shfl_xor(gd, 4, 8);
    float g = 1.f / (1.f + __expf(-gd));
#pragma unroll
    for (int c = 0; c < C; ++c) {
        float hh = fmaxf(g * sc[c] + (1.f - g) * outc[c], 0.f);
        OUT[(size_t)n * HC + h * C + c] = hh;
    }
}

// ---- fused gather+gate+classifier, H=1,C=64: 16 lanes/node, factorized ----
__global__ void gather64f_kernel(const int* __restrict__ rowptr,
                                 const int* __restrict__ srcp,
                                 const __half* __restrict__ eap,
                                 const float* __restrict__ we,
                                 const float* __restrict__ Q,
                                 const __half* __restrict__ K16,
                                 const __half* __restrict__ V16,
                                 const float* __restrict__ S,
                                 const float* __restrict__ wb,
                                 const float* __restrict__ wc,
                                 const float* __restrict__ bc,
                                 float* __restrict__ OUT,
                                 int N, float scale)
{
    int grp = (blockIdx.x * blockDim.x + threadIdx.x) >> 4;   // node
    int l16 = threadIdx.x & 15;
    if (grp >= N) return;
    int c0 = l16 << 2;

    float wv[8][4];
#pragma unroll
    for (int d = 0; d < 8; ++d) *(float4*)wv[d] = *(const float4*)(we + d * 64 + c0);
    float4 qv = *(const float4*)(Q + (size_t)grp * 64 + c0);
    float qe[8];
#pragma unroll
    for (int d = 0; d < 8; ++d) {
        float t = wv[d][0] * qv.x;
        t = fmaf(wv[d][1], qv.y, t);
        t = fmaf(wv[d][2], qv.z, t);
        t = fmaf(wv[d][3], qv.w, t);
        qe[d] = t;
    }

    float num0 = 0.f, num1 = 0.f, num2 = 0.f, num3 = 0.f, den = 0.f;
    float sacc[8];
#pragma unroll
    for (int d = 0; d < 8; ++d) sacc[d] = 0.f;

    int rs = rowptr[grp], re = rowptr[grp + 1];
    int j = rs;
    for (; j + 1 < re; j += 2) {
        int s0 = srcp[j], s1 = srcp[j + 1];
        float a0[8], a1[8];
        loadA(eap + (size_t)j * 8, a0);
        loadA(eap + (size_t)(j + 1) * 8, a1);
        uint2 ku0 = *(const uint2*)(K16 + (size_t)s0 * 64 + c0);
        uint2 vu0 = *(const uint2*)(V16 + (size_t)s0 * 64 + c0);
        uint2 ku1 = *(const uint2*)(K16 + (size_t)s1 * 64 + c0);
        uint2 vu1 = *(const uint2*)(V16 + (size_t)s1 * 64 + c0);
        float2 ka0 = H2F(ku0.x), kb0 = H2F(ku0.y);
        float2 va0 = H2F(vu0.x), vb0 = H2F(vu0.y);
        float2 ka1 = H2F(ku1.x), kb1 = H2F(ku1.y);
        float2 va1 = H2F(vu1.x), vb1 = H2F(vu1.y);
        float t0 = qv.x * ka0.x;
        t0 = fmaf(qv.y, ka0.y, t0); t0 = fmaf(qv.z, kb0.x, t0); t0 = fmaf(qv.w, kb0.y, t0);
        float t1 = qv.x * ka1.x;
        t1 = fmaf(qv.y, ka1.y, t1); t1 = fmaf(qv.z, kb1.x, t1); t1 = fmaf(qv.w, kb1.y, t1);
#pragma unroll
        for (int d = 0; d < 8; ++d) {
            t0 = fmaf(qe[d], a0[d], t0);
            t1 = fmaf(qe[d], a1[d], t1);
        }
#pragma unroll
        for (int off = 8; off > 0; off >>= 1) {
            t0 += __shfl_xor(t0, off, 16);
            t1 += __shfl_xor(t1, off, 16);
        }
        float ex0 = __expf(t0 * scale);
        float ex1 = __expf(t1 * scale);
        den += ex0 + ex1;
        num0 = fmaf(ex0, va0.x, fmaf(ex1, va1.x, num0));
        num1 = fmaf(ex0, va0.y, fmaf(ex1, va1.y, num1));
        num2 = fmaf(ex0, vb0.x, fmaf(ex1, vb1.x, num2));
        num3 = fmaf(ex0, vb0.y, fmaf(ex1, vb1.y, num3));
#pragma unroll
        for (int d = 0; d < 8; ++d)
            sacc[d] = fmaf(ex0, a0[d], fmaf(ex1, a1[d], sacc[d]));
    }
    if (j < re) {
        int s0 = srcp[j];
        float a0[8];
        loadA(eap + (size_t)j * 8, a0);
        uint2 ku0 = *(const uint2*)(K16 + (size_t)s0 * 64 + c0);
        uint2 vu0 = *(const uint2*)(V16 + (size_t)s0 * 64 + c0);
        float2 ka0 = H2F(ku0.x), kb0 = H2F(ku0.y);
        float2 va0 = H2F(vu0.x), vb0 = H2F(vu0.y);
        float t0 = qv.x * ka0.x;
        t0 = fmaf(qv.y, ka0.y, t0); t0 = fmaf(qv.z, kb0.x, t0); t0 = fmaf(qv.w, kb0.y, t0);
#pragma unroll
        for (int d = 0; d < 8; ++d) t0 = fmaf(qe[d], a0[d], t0);
#pragma unroll
        for (int off = 8; off > 0; off >>= 1) t0 += __shfl_xor(t0, off, 16);
        float ex0 = __expf(t0 * scale);
        den += ex0;
        num0 = fmaf(ex0, va0.x, num0);
        num1 = fmaf(ex0, va0.y, num1);
        num2 = fmaf(ex0, vb0.x, num2);
        num3 = fmaf(ex0, vb0.y, num3);
#pragma unroll
        for (int d = 0; d < 8; ++d) sacc[d] = fmaf(ex0, a0[d], sacc[d]);
    }

#pragma unroll
    for (int d = 0; d < 8; ++d) {
        num0 = fmaf(wv[d][0], sacc[d], num0);
        num1 = fmaf(wv[d][1], sacc[d], num1);
        num2 = fmaf(wv[d][2], sacc[d], num2);
        num3 = fmaf(wv[d][3], sacc[d], num3);
    }
    float inv = 1.f / (den + 1e-16f);
    float o0 = num0 * inv, o1 = num1 * inv, o2 = num2 * inv, o3 = num3 * inv;
    float4 sv  = *(const float4*)(S + (size_t)grp * 64 + c0);
    float4 wb0 = *(const float4*)(wb + c0);
    float4 wb1 = *(const float4*)(wb + 64 + c0);
    float4 wb2 = *(const float4*)(wb + 128 + c0);
    float gd = o0 * wb0.x + sv.x * wb1.x + (o0 - sv.x) * wb2.x;
    gd += o1 * wb0.y + sv.y * wb1.y + (o1 - sv.y) * wb2.y;
    gd += o2 * wb0.z + sv.z * wb1.z + (o2 - sv.z) * wb2.z;
    gd += o3 * wb0.w + sv.w * wb1.w + (o3 - sv.w) * wb2.w;
#pragma unroll
    for (int off = 8; off > 0; off >>= 1) gd += __shfl_xor(gd, off, 16);
    float g = 1.f / (1.f + __expf(-gd));
    float h0 = fmaxf(g * sv.x + (1.f - g) * o0, 0.f);
    float h1 = fmaxf(g * sv.y + (1.f - g) * o1, 0.f);
    float h2 = fmaxf(g * sv.z + (1.f - g) * o2, 0.f);
    float h3 = fmaxf(g * sv.w + (1.f - g) * o3, 0.f);
    float4 wcv = *(const float4*)(wc + c0);
    float t = h0 * wcv.x + h1 * wcv.y + h2 * wcv.z + h3 * wcv.w;
#pragma unroll
    for (int off = 8; off > 0; off >>= 1) t += __shfl_xor(t, off, 16);
    if (l16 == 0) OUT[grp] = t + bc[0];
}

extern "C" void kernel_launch(void* const* d_in, const int* in_sizes, int n_in,
                              void* d_out, int out_size, void* d_ws, size_t ws_size,
                              hipStream_t stream) {
    const float* x  = (const float*)d_in[0];
    const int*   ei = (const int*)d_in[1];
    const float* ea = (const float*)d_in[2];
    const int N = in_sizes[0] / 32;
    const int E = in_sizes[1] / 2;

    int p = 3;
    const float *wq1=(const float*)d_in[p+0], *bq1=(const float*)d_in[p+1],
                *wk1=(const float*)d_in[p+2], *bk1=(const float*)d_in[p+3],
                *wv1=(const float*)d_in[p+4], *bv1=(const float*)d_in[p+5],
                *we1=(const float*)d_in[p+6],
                *wsk1=(const float*)d_in[p+7], *bsk1=(const float*)d_in[p+8],
                *wb1=(const float*)d_in[p+9];
    p += 10;
    const float *wq2=(const float*)d_in[p+0], *bq2=(const float*)d_in[p+1],
                *wk2=(const float*)d_in[p+2], *bk2=(const float*)d_in[p+3],
                *wv2=(const float*)d_in[p+4], *bv2=(const float*)d_in[p+5],
                *we2=(const float*)d_in[p+6],
                *wsk2=(const float*)d_in[p+7], *bsk2=(const float*)d_in[p+8],
                *wb2=(const float*)d_in[p+9];
    p += 10;
    const float *wq3=(const float*)d_in[p+0], *bq3=(const float*)d_in[p+1],
                *wk3=(const float*)d_in[p+2], *bk3=(const float*)d_in[p+3],
                *wv3=(const float*)d_in[p+4], *bv3=(const float*)d_in[p+5],
                *we3=(const float*)d_in[p+6],
                *wsk3=(const float*)d_in[p+7], *bsk3=(const float*)d_in[p+8],
                *wb3=(const float*)d_in[p+9];
    p += 10;
    const float *wc = (const float*)d_in[p+0], *bc = (const float*)d_in[p+1];

    float* out = (float*)d_out;

    // ---- workspace layout ----
    float* ws = (float*)d_ws;
    float* Hb = ws;                               // N*48 fp32
    float* Qb = Hb + (size_t)N * 48;              // N*64 fp32
    float* Sb = Qb + (size_t)N * 64;              // N*64 fp32
    __half* KV16  = (__half*)(Sb + (size_t)N * 64);  // N*128 halfs
    __half* K3    = KV16;                          // layer3 K: N*64
    __half* V3    = KV16 + (size_t)N * 64;         // layer3 V: N*64
    __half* eap16 = KV16 + (size_t)N * 128;        // E*8 halfs
    int* ip      = (int*)(eap16 + (size_t)E * 8);
    int* rowptr  = ip;                 // N+2
    int* deg     = rowptr + (N + 2);   // N (cursor)
    int* bsum    = deg + N;            // 512
    int* boff    = bsum + 512;         // 512
    int* bcur    = boff + 512;         // up to 1024 buckets
    int* srcp    = bcur + 1024;        // E
    size_t buck_off = (size_t)((char*)(srcp + E) - (char*)d_ws);
    buck_off = (buck_off + 7) & ~(size_t)7;
    int2* buck = (int2*)((char*)d_ws + buck_off); // E records

    const int BLK = 256;
    const int NBLK = (N + SCAN_BLK - 1) / SCAN_BLK;
    const int NBUCK = (E + BW - 1) / BW;

    // ---------------- CSR build (bucketed scatter) ----------------
    hipMemsetAsync(deg, 0, (size_t)N * sizeof(int), stream);
    hipMemsetAsync(bcur, 0, (size_t)NBUCK * sizeof(int), stream);
    count_kernel<<<(E + BLK - 1) / BLK, BLK, 0, stream>>>(ei, deg, E);
    scan1_kernel<<<NBLK, SCAN_BLK, 0, stream>>>(deg, rowptr, bsum, N);
    scan2_kernel<<<1, 512, 0, stream>>>(bsum, boff, NBLK);
    scan3_kernel<<<(N + BLK - 1) / BLK, BLK, 0, stream>>>(rowptr, boff, N, E);
    hipMemsetAsync(deg, 0, (size_t)N * sizeof(int), stream);
    bucketA_kernel<<<(E + BLK - 1) / BLK, BLK, 0, stream>>>(ei, rowptr, deg, bcur, buck, E);
    bucketB_kernel<<<NBUCK, BLK, 0, stream>>>(buck, srcp, E);
    permuteE_kernel<<<(E + BLK - 1) / BLK, BLK, 0, stream>>>(ei, ea, srcp, eap16, E);

    // ------- layer 1: cin=32, H=8, C=6 (PK=16) -------
    proj8_kernel<32,6,16><<<(N*48 + BLK-1)/BLK, BLK, 0, stream>>>(
        x, wq1,bq1, wk1,bk1, wv1,bv1, wsk1,bsk1, Qb, KV16, Sb, N);
    gather8f_kernel<6,16><<<(N*8 + BLK-1)/BLK, BLK, 0, stream>>>(
        rowptr, srcp, eap16, we1, Qb, KV16, Sb, wb1, Hb, N, 1.0f/sqrtf(6.0f));

    // ------- layer 2: cin=48, H=8, C=3 (PK=8) -------
    proj8_kernel<48,3,8><<<(N*24 + BLK-1)/BLK, BLK, 0, stream>>>(
        Hb, wq2,bq2, wk2,bk2, wv2,bv2, wsk2,bsk2, Qb, KV16, Sb, N);
    gather8f_kernel<3,8><<<(N*8 + BLK-1)/BLK, BLK, 0, stream>>>(
        rowptr, srcp, eap16, we2, Qb, KV16, Sb, wb2, Hb, N, 1.0f/sqrtf(3.0f));

    // ------- layer 3: cin=24, H=1, C=64 -------
    proj64_kernel<<<(N*64 + BLK-1)/BLK, BLK, 0, stream>>>(
        Hb, wq3,bq3, wk3,bk3, wv3,bv3, wsk3,bsk3, Qb, K3, V3, Sb, N);
    gather64f_kernel<<<((size_t)N*16 + BLK-1)/BLK, BLK, 0, stream>>>(
        rowptr, srcp, eap16, we3, Qb, K3, V3, Sb, wb3, wc, bc, out, N, 1.0f/8.0f);
}

// Round 9
// 1053.527 us; speedup vs baseline: 2.0607x; 2.0607x over previous
//
#include <hip/hip_runtime.h>
#include <hip/hip_fp16.h>
#include <math.h>

#define SCAN_BLK 256
#define RCHUNK 4096            // edges per radix block
#define NBUCK 256              // radix buckets
#define NSPLIT 8               // blocks per bucket in bscatter

__device__ __forceinline__ float2 H2F(unsigned u) {
    __half2 h = *reinterpret_cast<__half2*>(&u);
    return __half22float2(h);
}
__device__ __forceinline__ unsigned F2H(float a, float b) {
    __half2 h = __floats2half2_rn(a, b);
    return *reinterpret_cast<unsigned*>(&h);
}

// unpack 8 fp16 edge attrs
__device__ __forceinline__ void loadA(const __half* p, float* a) {
    uint4 u = *(const uint4*)p;
    float2 t;
    t = H2F(u.x); a[0] = t.x; a[1] = t.y;
    t = H2F(u.y); a[2] = t.x; a[3] = t.y;
    t = H2F(u.z); a[4] = t.x; a[5] = t.y;
    t = H2F(u.w); a[6] = t.x; a[7] = t.y;
}

// packed per-head K/V fp16 packet
template<int C>
__device__ __forceinline__ void loadKV(const __half* p, float* k, float* v) {
    if constexpr (C == 6) {
        uint4 p0 = *(const uint4*)p;
        uint4 p1 = *(const uint4*)(p + 8);
        float2 t;
        t = H2F(p0.x); k[0] = t.x; k[1] = t.y;
        t = H2F(p0.y); k[2] = t.x; k[3] = t.y;
        t = H2F(p0.z); k[4] = t.x; k[5] = t.y;
        t = H2F(p0.w); v[0] = t.x; v[1] = t.y;
        t = H2F(p1.x); v[2] = t.x; v[3] = t.y;
        t = H2F(p1.y); v[4] = t.x; v[5] = t.y;
    } else {  // C == 3
        uint4 p0 = *(const uint4*)p;
        float2 t;
        t = H2F(p0.x); k[0] = t.x; k[1] = t.y;
        t = H2F(p0.y); k[2] = t.x; v[0] = t.y;
        t = H2F(p0.z); v[1] = t.x; v[2] = t.y;
    }
}

// ---------------- CSR rowptr build ----------------
__global__ void count_kernel(const int* __restrict__ ei, int* __restrict__ deg, int E) {
    int e = blockIdx.x * blockDim.x + threadIdx.x;
    if (e < E) atomicAdd(&deg[ei[E + e]], 1);
}

__global__ void scan1_kernel(const int* __restrict__ deg, int* __restrict__ part,
                             int* __restrict__ bsum, int N) {
    __shared__ int sm[SCAN_BLK];
    int i = blockIdx.x * SCAN_BLK + threadIdx.x;
    int v = (i < N) ? deg[i] : 0;
    sm[threadIdx.x] = v;
    __syncthreads();
    for (int off = 1; off < SCAN_BLK; off <<= 1) {
        int t = (threadIdx.x >= off) ? sm[threadIdx.x - off] : 0;
        __syncthreads();
        sm[threadIdx.x] += t;
        __syncthreads();
    }
    if (i < N) part[i] = sm[threadIdx.x] - v;
    if (threadIdx.x == SCAN_BLK - 1) bsum[blockIdx.x] = sm[threadIdx.x];
}

__global__ void scan2_kernel(const int* __restrict__ bsum, int* __restrict__ boff, int nb) {
    __shared__ int sm[512];
    int v = (threadIdx.x < nb) ? bsum[threadIdx.x] : 0;
    sm[threadIdx.x] = v;
    __syncthreads();
    for (int off = 1; off < 512; off <<= 1) {
        int t = (threadIdx.x >= off) ? sm[threadIdx.x - off] : 0;
        __syncthreads();
        sm[threadIdx.x] += t;
        __syncthreads();
    }
    if (threadIdx.x < nb) boff[threadIdx.x] = sm[threadIdx.x] - v;
}

__global__ void scan3_kernel(int* __restrict__ rowptr, const int* __restrict__ boff,
                             int N, int E) {
    int i = blockIdx.x * blockDim.x + threadIdx.x;
    if (i < N) rowptr[i] += boff[i / SCAN_BLK];
    if (i == 0) rowptr[N] = E;
}

// ---------------- radix bucket pass (by dst >> shift) ----------------
// pass 1: per-block histogram (LDS atomics only) -> hist[bucket*nblk + blk]
__global__ void histA_kernel(const int* __restrict__ ei, int* __restrict__ hist,
                             int E, int shift, int nblk) {
    __shared__ int h[NBUCK];
    h[threadIdx.x] = 0;
    __syncthreads();
    int base = blockIdx.x * RCHUNK;
#pragma unroll
    for (int r = 0; r < RCHUNK / 256; ++r) {
        int i = base + r * 256 + threadIdx.x;
        if (i < E) atomicAdd(&h[ei[E + i] >> shift], 1);
    }
    __syncthreads();
    hist[threadIdx.x * nblk + blockIdx.x] = h[threadIdx.x];
}

// pass 2: per-bucket exclusive scan over blocks; total -> btot[bucket]
__global__ void scanB_kernel(int* __restrict__ hist, int* __restrict__ btot, int nblk) {
    __shared__ int sm[1024];
    int b = blockIdx.x;
    int tid = threadIdx.x;
    int v = (tid < nblk) ? hist[b * nblk + tid] : 0;
    sm[tid] = v;
    __syncthreads();
    for (int off = 1; off < 1024; off <<= 1) {
        int t = (tid >= off) ? sm[tid - off] : 0;
        __syncthreads();
        sm[tid] += t;
        __syncthreads();
    }
    if (tid < nblk) hist[b * nblk + tid] = sm[tid] - v;   // exclusive
    if (tid == 1023) btot[b] = sm[1023];
}

// pass 3: exclusive scan of bucket totals -> bbase
__global__ void scanC_kernel(const int* __restrict__ btot, int* __restrict__ bbase) {
    __shared__ int sm[NBUCK];
    int tid = threadIdx.x;
    int v = btot[tid];
    sm[tid] = v;
    __syncthreads();
    for (int off = 1; off < NBUCK; off <<= 1) {
        int t = (tid >= off) ? sm[tid - off] : 0;
        __syncthreads();
        sm[tid] += t;
        __syncthreads();
    }
    bbase[tid] = sm[tid] - v;
}

// pass 4: reorder (dst, eid) into bucket-grouped array; LDS-ranked chunk writes
__global__ void reorderB_kernel(const int* __restrict__ ei, const int* __restrict__ hist,
                                const int* __restrict__ bbase, int2* __restrict__ sorted,
                                int E, int shift, int nblk) {
    __shared__ int off[NBUCK];
    off[threadIdx.x] = bbase[threadIdx.x] + hist[threadIdx.x * nblk + blockIdx.x];
    __syncthreads();
    int base = blockIdx.x * RCHUNK;
#pragma unroll
    for (int r = 0; r < RCHUNK / 256; ++r) {
        int i = base + r * 256 + threadIdx.x;
        if (i < E) {
            int dst = ei[E + i];
            int k = atomicAdd(&off[dst >> shift], 1);
            sorted[k] = make_int2(dst, i);
        }
    }
}

// pass 5: per-bucket exact CSR placement + fused ea gather + fp16 cvt.
// bucket = bid&255 keeps all NSPLIT splits of one bucket on the same XCD
// (blockIdx%8 -> XCD), so srcp/eap window writes merge in one L2.
__global__ void bscatter_kernel(const int2* __restrict__ sorted,
                                const int* __restrict__ bbase, const int* __restrict__ btot,
                                const int* __restrict__ rowptr, int* __restrict__ cursor,
                                const int* __restrict__ ei, const float* __restrict__ ea,
                                int* __restrict__ srcp, __half* __restrict__ eap, int E) {
    int b = blockIdx.x & (NBUCK - 1);
    int split = blockIdx.x >> 8;
    int s = bbase[b], cnt = btot[b];
    int i0 = (int)((long long)cnt * split / NSPLIT);
    int i1 = (int)((long long)cnt * (split + 1) / NSPLIT);
    for (int i = i0 + threadIdx.x; i < i1; i += blockDim.x) {
        int2 r = sorted[s + i];
        int pos = atomicAdd(&cursor[r.x], 1);
        int slot = rowptr[r.x] + pos;
        srcp[slot] = ei[r.y];
        float4 a0 = *(const float4*)(ea + (size_t)r.y * 8);
        float4 a1 = *(const float4*)(ea + (size_t)r.y * 8 + 4);
        uint4 u;
        u.x = F2H(a0.x, a0.y);
        u.y = F2H(a0.z, a0.w);
        u.z = F2H(a1.x, a1.y);
        u.w = F2H(a1.z, a1.w);
        *(uint4*)(eap + (size_t)slot * 8) = u;
    }
}

// ------- projections, H=8 layers: Q,S fp32 unpadded; KV fp16 packed -------
template<int CIN, int C, int PK>
__global__ void proj8_kernel(const float* __restrict__ X,
                             const float* __restrict__ wq, const float* __restrict__ bq,
                             const float* __restrict__ wk, const float* __restrict__ bk,
                             const float* __restrict__ wv, const float* __restrict__ bv,
                             const float* __restrict__ wsk, const float* __restrict__ bsk,
                             float* __restrict__ Q, __half* __restrict__ KV,
                             float* __restrict__ S, int N)
{
    const int HC = 8 * C;
    int idx = blockIdx.x * blockDim.x + threadIdx.x;
    if (idx >= N * HC) return;
    int n = idx / HC;
    int c = idx - n * HC;
    int h = c / C;
    int cc = c - h * C;
    float q = bq[c], k = bk[c], v = bv[c], s = bsk[c];
    const float* xr = X + (size_t)n * CIN;
#pragma unroll
    for (int i = 0; i < CIN; ++i) {
        float xi = xr[i];
        q = fmaf(xi, wq[i * HC + c], q);
        k = fmaf(xi, wk[i * HC + c], k);
        v = fmaf(xi, wv[i * HC + c], v);
        s = fmaf(xi, wsk[i * HC + c], s);
    }
    Q[(size_t)n * HC + c] = q;
    __half* kp = KV + (size_t)n * (8 * PK) + h * PK;
    kp[cc] = __float2half_rn(k);
    kp[C + cc] = __float2half_rn(v);
    S[(size_t)n * HC + c] = s;
}

// ------- projection, layer3: Q,S fp32; K,V fp16 rows of 64 -------
__global__ void proj64_kernel(const float* __restrict__ X,
                              const float* __restrict__ wq, const float* __restrict__ bq,
                              const float* __restrict__ wk, const float* __restrict__ bk,
                              const float* __restrict__ wv, const float* __restrict__ bv,
                              const float* __restrict__ wsk, const float* __restrict__ bsk,
                              float* __restrict__ Q, __half* __restrict__ K16,
                              __half* __restrict__ V16, float* __restrict__ S, int N)
{
    int idx = blockIdx.x * blockDim.x + threadIdx.x;
    if (idx >= N * 64) return;
    int n = idx >> 6;
    int c = idx & 63;
    float q = bq[c], k = bk[c], v = bv[c], s = bsk[c];
    const float* xr = X + (size_t)n * 24;
#pragma unroll
    for (int i = 0; i < 24; ++i) {
        float xi = xr[i];
        q = fmaf(xi, wq[i * 64 + c], q);
        k = fmaf(xi, wk[i * 64 + c], k);
        v = fmaf(xi, wv[i * 64 + c], v);
        s = fmaf(xi, wsk[i * 64 + c], s);
    }
    Q[idx] = q;
    K16[idx] = __float2half_rn(k);
    V16[idx] = __float2half_rn(v);
    S[idx] = s;
}

// ---- fused gather+gate, H=8: thread per (node, head), factorized e -----
template<int C, int PK>
__global__ void gather8f_kernel(const int* __restrict__ rowptr,
                                const int* __restrict__ srcp,
                                const __half* __restrict__ eap,
                                const float* __restrict__ we,
                                const float* __restrict__ Q,
                                const __half* __restrict__ KV,
                                const float* __restrict__ S,
                                const float* __restrict__ wb,
                                float* __restrict__ OUT,
                                int N, float scale)
{
    const int HC = 8 * C;
    int tid = blockIdx.x * blockDim.x + threadIdx.x;
    int n = tid >> 3;
    int h = tid & 7;
    if (n >= N) return;

    float q[C];
    const float* Qp = Q + (size_t)n * HC + h * C;
#pragma unroll
    for (int c = 0; c < C; ++c) q[c] = Qp[c];

    float qe[8];
#pragma unroll
    for (int d = 0; d < 8; ++d) {
        float t = 0.f;
#pragma unroll
        for (int c = 0; c < C; ++c) t = fmaf(we[d * HC + h * C + c], q[c], t);
        qe[d] = t;
    }

    float num[C];
#pragma unroll
    for (int c = 0; c < C; ++c) num[c] = 0.f;
    float sacc[8];
#pragma unroll
    for (int d = 0; d < 8; ++d) sacc[d] = 0.f;
    float den = 0.f;

    int rs = rowptr[n], re = rowptr[n + 1];
    int j = rs;
    for (; j + 1 < re; j += 2) {
        int s0 = srcp[j], s1 = srcp[j + 1];
        float a0[8], a1[8];
        loadA(eap + (size_t)j * 8, a0);
        loadA(eap + (size_t)(j + 1) * 8, a1);
        float k0[C], v0[C], k1[C], v1[C];
        loadKV<C>(KV + (size_t)s0 * (8 * PK) + h * PK, k0, v0);
        loadKV<C>(KV + (size_t)s1 * (8 * PK) + h * PK, k1, v1);
        float d0 = 0.f, d1 = 0.f;
#pragma unroll
        for (int c = 0; c < C; ++c) {
            d0 = fmaf(q[c], k0[c], d0);
            d1 = fmaf(q[c], k1[c], d1);
        }
        float qa0 = 0.f, qa1 = 0.f;
#pragma unroll
        for (int d = 0; d < 8; ++d) {
            qa0 = fmaf(qe[d], a0[d], qa0);
            qa1 = fmaf(qe[d], a1[d], qa1);
        }
        float ex0 = __expf((d0 + qa0) * scale);
        float ex1 = __expf((d1 + qa1) * scale);
        den += ex0 + ex1;
#pragma unroll
        for (int c = 0; c < C; ++c) {
            num[c] = fmaf(ex0, v0[c], num[c]);
            num[c] = fmaf(ex1, v1[c], num[c]);
        }
#pragma unroll
        for (int d = 0; d < 8; ++d)
            sacc[d] = fmaf(ex0, a0[d], fmaf(ex1, a1[d], sacc[d]));
    }
    if (j < re) {
        int s0 = srcp[j];
        float a0[8];
        loadA(eap + (size_t)j * 8, a0);
        float k0[C], v0[C];
        loadKV<C>(KV + (size_t)s0 * (8 * PK) + h * PK, k0, v0);
        float d0 = 0.f;
#pragma unroll
        for (int c = 0; c < C; ++c) d0 = fmaf(q[c], k0[c], d0);
        float qa0 = 0.f;
#pragma unroll
        for (int d = 0; d < 8; ++d) qa0 = fmaf(qe[d], a0[d], qa0);
        float ex0 = __expf((d0 + qa0) * scale);
        den += ex0;
#pragma unroll
        for (int c = 0; c < C; ++c) num[c] = fmaf(ex0, v0[c], num[c]);
#pragma unroll
        for (int d = 0; d < 8; ++d) sacc[d] = fmaf(ex0, a0[d], sacc[d]);
    }

    float inv = 1.f / (den + 1e-16f);
    float outc[C], sc[C];
    float gd = 0.f;
#pragma unroll
    for (int c = 0; c < C; ++c) {
        float e_ = 0.f;
#pragma unroll
        for (int d = 0; d < 8; ++d) e_ = fmaf(we[d * HC + h * C + c], sacc[d], e_);
        float o = (num[c] + e_) * inv;
        float s_ = S[(size_t)n * HC + h * C + c];
        outc[c] = o;
        sc[c] = s_;
        gd += o * wb[h * C + c] + s_ * wb[HC + h * C + c] + (o - s_) * wb[2 * HC + h * C + c];
    }
    gd += __shfl_xor(gd, 1, 8);
    gd += __shfl_xor(gd, 2, 8);
    gd += __shfl_xor(gd, 4, 8);
    float g = 1.f / (1.f + __expf(-gd));
#pragma unroll
    for (int c = 0; c < C; ++c) {
        float hh = fmaxf(g * sc[c] + (1.f - g) * outc[c], 0.f);
        OUT[(size_t)n * HC + h * C + c] = hh;
    }
}

// ---- fused gather+gate+classifier, H=1,C=64: 16 lanes/node, factorized ----
__global__ void gather64f_kernel(const int* __restrict__ rowptr,
                                 const int* __restrict__ srcp,
                                 const __half* __restrict__ eap,
                                 const float* __restrict__ we,
                                 const float* __restrict__ Q,
                                 const __half* __restrict__ K16,
                                 const __half* __restrict__ V16,
                                 const float* __restrict__ S,
                                 const float* __restrict__ wb,
                                 const float* __restrict__ wc,
                                 const float* __restrict__ bc,
                                 float* __restrict__ OUT,
                                 int N, float scale)
{
    int grp = (blockIdx.x * blockDim.x + threadIdx.x) >> 4;   // node
    int l16 = threadIdx.x & 15;
    if (grp >= N) return;
    int c0 = l16 << 2;

    float wv[8][4];
#pragma unroll
    for (int d = 0; d < 8; ++d) *(float4*)wv[d] = *(const float4*)(we + d * 64 + c0);
    float4 qv = *(const float4*)(Q + (size_t)grp * 64 + c0);
    float qe[8];
#pragma unroll
    for (int d = 0; d < 8; ++d) {
        float t = wv[d][0] * qv.x;
        t = fmaf(wv[d][1], qv.y, t);
        t = fmaf(wv[d][2], qv.z, t);
        t = fmaf(wv[d][3], qv.w, t);
        qe[d] = t;
    }

    float num0 = 0.f, num1 = 0.f, num2 = 0.f, num3 = 0.f, den = 0.f;
    float sacc[8];
#pragma unroll
    for (int d = 0; d < 8; ++d) sacc[d] = 0.f;

    int rs = rowptr[grp], re = rowptr[grp + 1];
    int j = rs;
    for (; j + 1 < re; j += 2) {
        int s0 = srcp[j], s1 = srcp[j + 1];
        float a0[8], a1[8];
        loadA(eap + (size_t)j * 8, a0);
        loadA(eap + (size_t)(j + 1) * 8, a1);
        uint2 ku0 = *(const uint2*)(K16 + (size_t)s0 * 64 + c0);
        uint2 vu0 = *(const uint2*)(V16 + (size_t)s0 * 64 + c0);
        uint2 ku1 = *(const uint2*)(K16 + (size_t)s1 * 64 + c0);
        uint2 vu1 = *(const uint2*)(V16 + (size_t)s1 * 64 + c0);
        float2 ka0 = H2F(ku0.x), kb0 = H2F(ku0.y);
        float2 va0 = H2F(vu0.x), vb0 = H2F(vu0.y);
        float2 ka1 = H2F(ku1.x), kb1 = H2F(ku1.y);
        float2 va1 = H2F(vu1.x), vb1 = H2F(vu1.y);
        float t0 = qv.x * ka0.x;
        t0 = fmaf(qv.y, ka0.y, t0); t0 = fmaf(qv.z, kb0.x, t0); t0 = fmaf(qv.w, kb0.y, t0);
        float t1 = qv.x * ka1.x;
        t1 = fmaf(qv.y, ka1.y, t1); t1 = fmaf(qv.z, kb1.x, t1); t1 = fmaf(qv.w, kb1.y, t1);
#pragma unroll
        for (int d = 0; d < 8; ++d) {
            t0 = fmaf(qe[d], a0[d], t0);
            t1 = fmaf(qe[d], a1[d], t1);
        }
#pragma unroll
        for (int off = 8; off > 0; off >>= 1) {
            t0 += __shfl_xor(t0, off, 16);
            t1 += __shfl_xor(t1, off, 16);
        }
        float ex0 = __expf(t0 * scale);
        float ex1 = __expf(t1 * scale);
        den += ex0 + ex1;
        num0 = fmaf(ex0, va0.x, fmaf(ex1, va1.x, num0));
        num1 = fmaf(ex0, va0.y, fmaf(ex1, va1.y, num1));
        num2 = fmaf(ex0, vb0.x, fmaf(ex1, vb1.x, num2));
        num3 = fmaf(ex0, vb0.y, fmaf(ex1, vb1.y, num3));
#pragma unroll
        for (int d = 0; d < 8; ++d)
            sacc[d] = fmaf(ex0, a0[d], fmaf(ex1, a1[d], sacc[d]));
    }
    if (j < re) {
        int s0 = srcp[j];
        float a0[8];
        loadA(eap + (size_t)j * 8, a0);
        uint2 ku0 = *(const uint2*)(K16 + (size_t)s0 * 64 + c0);
        uint2 vu0 = *(const uint2*)(V16 + (size_t)s0 * 64 + c0);
        float2 ka0 = H2F(ku0.x), kb0 = H2F(ku0.y);
        float2 va0 = H2F(vu0.x), vb0 = H2F(vu0.y);
        float t0 = qv.x * ka0.x;
        t0 = fmaf(qv.y, ka0.y, t0); t0 = fmaf(qv.z, kb0.x, t0); t0 = fmaf(qv.w, kb0.y, t0);
#pragma unroll
        for (int d = 0; d < 8; ++d) t0 = fmaf(qe[d], a0[d], t0);
#pragma unroll
        for (int off = 8; off > 0; off >>= 1) t0 += __shfl_xor(t0, off, 16);
        float ex0 = __expf(t0 * scale);
        den += ex0;
        num0 = fmaf(ex0, va0.x, num0);
        num1 = fmaf(ex0, va0.y, num1);
        num2 = fmaf(ex0, vb0.x, num2);
        num3 = fmaf(ex0, vb0.y, num3);
#pragma unroll
        for (int d = 0; d < 8; ++d) sacc[d] = fmaf(ex0, a0[d], sacc[d]);
    }

#pragma unroll
    for (int d = 0; d < 8; ++d) {
        num0 = fmaf(wv[d][0], sacc[d], num0);
        num1 = fmaf(wv[d][1], sacc[d], num1);
        num2 = fmaf(wv[d][2], sacc[d], num2);
        num3 = fmaf(wv[d][3], sacc[d], num3);
    }
    float inv = 1.f / (den + 1e-16f);
    float o0 = num0 * inv, o1 = num1 * inv, o2 = num2 * inv, o3 = num3 * inv;
    float4 sv  = *(const float4*)(S + (size_t)grp * 64 + c0);
    float4 wb0 = *(const float4*)(wb + c0);
    float4 wb1 = *(const float4*)(wb + 64 + c0);
    float4 wb2 = *(const float4*)(wb + 128 + c0);
    float gd = o0 * wb0.x + sv.x * wb1.x + (o0 - sv.x) * wb2.x;
    gd += o1 * wb0.y + sv.y * wb1.y + (o1 - sv.y) * wb2.y;
    gd += o2 * wb0.z + sv.z * wb1.z + (o2 - sv.z) * wb2.z;
    gd += o3 * wb0.w + sv.w * wb1.w + (o3 - sv.w) * wb2.w;
#pragma unroll
    for (int off = 8; off > 0; off >>= 1) gd += __shfl_xor(gd, off, 16);
    float g = 1.f / (1.f + __expf(-gd));
    float h0 = fmaxf(g * sv.x + (1.f - g) * o0, 0.f);
    float h1 = fmaxf(g * sv.y + (1.f - g) * o1, 0.f);
    float h2 = fmaxf(g * sv.z + (1.f - g) * o2, 0.f);
    float h3 = fmaxf(g * sv.w + (1.f - g) * o3, 0.f);
    float4 wcv = *(const float4*)(wc + c0);
    float t = h0 * wcv.x + h1 * wcv.y + h2 * wcv.z + h3 * wcv.w;
#pragma unroll
    for (int off = 8; off > 0; off >>= 1) t += __shfl_xor(t, off, 16);
    if (l16 == 0) OUT[grp] = t + bc[0];
}

extern "C" void kernel_launch(void* const* d_in, const int* in_sizes, int n_in,
                              void* d_out, int out_size, void* d_ws, size_t ws_size,
                              hipStream_t stream) {
    const float* x  = (const float*)d_in[0];
    const int*   ei = (const int*)d_in[1];
    const float* ea = (const float*)d_in[2];
    const int N = in_sizes[0] / 32;
    const int E = in_sizes[1] / 2;

    int p = 3;
    const float *wq1=(const float*)d_in[p+0], *bq1=(const float*)d_in[p+1],
                *wk1=(const float*)d_in[p+2], *bk1=(const float*)d_in[p+3],
                *wv1=(const float*)d_in[p+4], *bv1=(const float*)d_in[p+5],
                *we1=(const float*)d_in[p+6],
                *wsk1=(const float*)d_in[p+7], *bsk1=(const float*)d_in[p+8],
                *wb1=(const float*)d_in[p+9];
    p += 10;
    const float *wq2=(const float*)d_in[p+0], *bq2=(const float*)d_in[p+1],
                *wk2=(const float*)d_in[p+2], *bk2=(const float*)d_in[p+3],
                *wv2=(const float*)d_in[p+4], *bv2=(const float*)d_in[p+5],
                *we2=(const float*)d_in[p+6],
                *wsk2=(const float*)d_in[p+7], *bsk2=(const float*)d_in[p+8],
                *wb2=(const float*)d_in[p+9];
    p += 10;
    const float *wq3=(const float*)d_in[p+0], *bq3=(const float*)d_in[p+1],
                *wk3=(const float*)d_in[p+2], *bk3=(const float*)d_in[p+3],
                *wv3=(const float*)d_in[p+4], *bv3=(const float*)d_in[p+5],
                *we3=(const float*)d_in[p+6],
                *wsk3=(const float*)d_in[p+7], *bsk3=(const float*)d_in[p+8],
                *wb3=(const float*)d_in[p+9];
    p += 10;
    const float *wc = (const float*)d_in[p+0], *bc = (const float*)d_in[p+1];

    float* out = (float*)d_out;

    // ---- workspace layout ----
    float* ws = (float*)d_ws;
    float* Hb = ws;                               // N*48 fp32
    float* Qb = Hb + (size_t)N * 48;              // N*64 fp32
    float* Sb = Qb + (size_t)N * 64;              // N*64 fp32
    __half* KV16  = (__half*)(Sb + (size_t)N * 64);  // N*128 halfs
    __half* K3    = KV16;
    __half* V3    = KV16 + (size_t)N * 64;
    __half* eap16 = KV16 + (size_t)N * 128;       // E*8 halfs
    int* ip      = (int*)(eap16 + (size_t)E * 8);
    int* rowptr  = ip;                 // N+2
    int* deg     = rowptr + (N + 2);   // N (cursor)
    int* bsum    = deg + N;            // 512
    int* boff    = bsum + 512;         // 512
    int* btot    = boff + 512;         // 256
    int* bbase   = btot + 256;         // 256
    int* srcp    = bbase + 256;        // E
    int* hist    = srcp + E;           // NBUCK * nblkR
    // sorted aliases Qb (consumed by bscatter before proj writes Qb)
    int2* sorted = (int2*)Qb;          // E records (E*8B <= N*64*4B since E<=8N... 3.2M*8=25.6MB == N*64*4B)

    const int BLK = 256;
    const int NBLK = (N + SCAN_BLK - 1) / SCAN_BLK;
    const int nblkR = (E + RCHUNK - 1) / RCHUNK;  // <= 1024 assumed

    int shift = 0;
    while (((N - 1) >> shift) >= NBUCK) shift++;

    // ---------------- rowptr ----------------
    hipMemsetAsync(deg, 0, (size_t)N * sizeof(int), stream);
    count_kernel<<<(E + BLK - 1) / BLK, BLK, 0, stream>>>(ei, deg, E);
    scan1_kernel<<<NBLK, SCAN_BLK, 0, stream>>>(deg, rowptr, bsum, N);
    scan2_kernel<<<1, 512, 0, stream>>>(bsum, boff, NBLK);
    scan3_kernel<<<(N + BLK - 1) / BLK, BLK, 0, stream>>>(rowptr, boff, N, E);

    // ---------------- radix bucket + merged scatter ----------------
    histA_kernel<<<nblkR, NBUCK, 0, stream>>>(ei, hist, E, shift, nblkR);
    scanB_kernel<<<NBUCK, 1024, 0, stream>>>(hist, btot, nblkR);
    scanC_kernel<<<1, NBUCK, 0, stream>>>(btot, bbase);
    reorderB_kernel<<<nblkR, NBUCK, 0, stream>>>(ei, hist, bbase, sorted, E, shift, nblkR);
    hipMemsetAsync(deg, 0, (size_t)N * sizeof(int), stream);
    bscatter_kernel<<<NBUCK * NSPLIT, BLK, 0, stream>>>(
        sorted, bbase, btot, rowptr, deg, ei, ea, srcp, eap16, E);

    // ------- layer 1: cin=32, H=8, C=6 (PK=16) -------
    proj8_kernel<32,6,16><<<(N*48 + BLK-1)/BLK, BLK, 0, stream>>>(
        x, wq1,bq1, wk1,bk1, wv1,bv1, wsk1,bsk1, Qb, KV16, Sb, N);
    gather8f_kernel<6,16><<<(N*8 + BLK-1)/BLK, BLK, 0, stream>>>(
        rowptr, srcp, eap16, we1, Qb, KV16, Sb, wb1, Hb, N, 1.0f/sqrtf(6.0f));

    // ------- layer 2: cin=48, H=8, C=3 (PK=8) -------
    proj8_kernel<48,3,8><<<(N*24 + BLK-1)/BLK, BLK, 0, stream>>>(
        Hb, wq2,bq2, wk2,bk2, wv2,bv2, wsk2,bsk2, Qb, KV16, Sb, N);
    gather8f_kernel<3,8><<<(N*8 + BLK-1)/BLK, BLK, 0, stream>>>(
        rowptr, srcp, eap16, we2, Qb, KV16, Sb, wb2, Hb, N, 1.0f/sqrtf(3.0f));

    // ------- layer 3: cin=24, H=1, C=64 -------
    proj64_kernel<<<(N*64 + BLK-1)/BLK, BLK, 0, stream>>>(
        Hb, wq3,bq3, wk3,bk3, wv3,bv3, wsk3,bsk3, Qb, K3, V3, Sb, N);
    gather64f_kernel<<<((size_t)N*16 + BLK-1)/BLK, BLK, 0, stream>>>(
        rowptr, srcp, eap16, we3, Qb, K3, V3, Sb, wb3, wc, bc, out, N, 1.0f/8.0f);
}

// Round 10
// 818.988 us; speedup vs baseline: 2.6508x; 1.2864x over previous
//
#include <hip/hip_runtime.h>
#include <hip/hip_fp16.h>
#include <math.h>

#define RCHUNK 8192            // edges per radix block
#define NBUCK 512              // max radix buckets (bucket = 256 dst)
#define CAP 12288              // LDS tmp capacity per bucket (mean 8184 + 45 sigma)

__device__ __forceinline__ float2 H2F(unsigned u) {
    __half2 h = *reinterpret_cast<__half2*>(&u);
    return __half22float2(h);
}
__device__ __forceinline__ unsigned F2H(float a, float b) {
    __half2 h = __floats2half2_rn(a, b);
    return *reinterpret_cast<unsigned*>(&h);
}

// unpack 8 fp16 edge attrs
__device__ __forceinline__ void loadA(const __half* p, float* a) {
    uint4 u = *(const uint4*)p;
    float2 t;
    t = H2F(u.x); a[0] = t.x; a[1] = t.y;
    t = H2F(u.y); a[2] = t.x; a[3] = t.y;
    t = H2F(u.z); a[4] = t.x; a[5] = t.y;
    t = H2F(u.w); a[6] = t.x; a[7] = t.y;
}

// packed per-head K/V fp16 packet
template<int C>
__device__ __forceinline__ void loadKV(const __half* p, float* k, float* v) {
    if constexpr (C == 6) {
        uint4 p0 = *(const uint4*)p;
        uint4 p1 = *(const uint4*)(p + 8);
        float2 t;
        t = H2F(p0.x); k[0] = t.x; k[1] = t.y;
        t = H2F(p0.y); k[2] = t.x; k[3] = t.y;
        t = H2F(p0.z); k[4] = t.x; k[5] = t.y;
        t = H2F(p0.w); v[0] = t.x; v[1] = t.y;
        t = H2F(p1.x); v[2] = t.x; v[3] = t.y;
        t = H2F(p1.y); v[4] = t.x; v[5] = t.y;
    } else {  // C == 3
        uint4 p0 = *(const uint4*)p;
        float2 t;
        t = H2F(p0.x); k[0] = t.x; k[1] = t.y;
        t = H2F(p0.y); k[2] = t.x; v[0] = t.y;
        t = H2F(p0.z); v[1] = t.x; v[2] = t.y;
    }
}

// ---- pass 1: per-block histogram over 512 buckets (LDS atomics only) ----
__global__ void histA_kernel(const int* __restrict__ ei, int* __restrict__ hist,
                             int E, int nblk) {
    __shared__ int h[NBUCK];
    h[threadIdx.x] = 0;
    h[threadIdx.x + 256] = 0;
    __syncthreads();
    int base = blockIdx.x * RCHUNK;
#pragma unroll
    for (int r = 0; r < RCHUNK / 256; ++r) {
        int i = base + r * 256 + threadIdx.x;
        if (i < E) atomicAdd(&h[ei[E + i] >> 8], 1);
    }
    __syncthreads();
    hist[threadIdx.x * nblk + blockIdx.x] = h[threadIdx.x];
    hist[(threadIdx.x + 256) * nblk + blockIdx.x] = h[threadIdx.x + 256];
}

// ---- pass 2: per-bucket exclusive scan over blocks; total -> btot ----
__global__ void scanB_kernel(int* __restrict__ hist, int* __restrict__ btot, int nblk) {
    __shared__ int sm[1024];
    int b = blockIdx.x;
    int tid = threadIdx.x;
    int v = (tid < nblk) ? hist[b * nblk + tid] : 0;
    sm[tid] = v;
    __syncthreads();
    for (int off = 1; off < 1024; off <<= 1) {
        int t = (tid >= off) ? sm[tid - off] : 0;
        __syncthreads();
        sm[tid] += t;
        __syncthreads();
    }
    if (tid < nblk) hist[b * nblk + tid] = sm[tid] - v;   // exclusive
    if (tid == 1023) btot[b] = sm[1023];
}

// ---- pass 3: exclusive scan of bucket totals -> bbase (== rowptr[b<<8]) ----
__global__ void scanC_kernel(const int* __restrict__ btot, int* __restrict__ bbase) {
    __shared__ int sm[NBUCK];
    int tid = threadIdx.x;
    int v = btot[tid];
    sm[tid] = v;
    __syncthreads();
    for (int off = 1; off < NBUCK; off <<= 1) {
        int t = (tid >= off) ? sm[tid - off] : 0;
        __syncthreads();
        sm[tid] += t;
        __syncthreads();
    }
    bbase[tid] = sm[tid] - v;
}

// ---- pass 4: reorder packed (dstlo<<24 | eid) into bucket-grouped array ----
__global__ void reorderB_kernel(const int* __restrict__ ei, const int* __restrict__ hist,
                                const int* __restrict__ bbase, unsigned* __restrict__ sorted,
                                int E, int nblk) {
    __shared__ int off[NBUCK];
    off[threadIdx.x] = bbase[threadIdx.x] + hist[threadIdx.x * nblk + blockIdx.x];
    off[threadIdx.x + 256] = bbase[threadIdx.x + 256] + hist[(threadIdx.x + 256) * nblk + blockIdx.x];
    __syncthreads();
    int base = blockIdx.x * RCHUNK;
#pragma unroll
    for (int r = 0; r < RCHUNK / 256; ++r) {
        int i = base + r * 256 + threadIdx.x;
        if (i < E) {
            int dst = ei[E + i];
            int k = atomicAdd(&off[dst >> 8], 1);
            sorted[k] = ((unsigned)(dst & 255) << 24) | (unsigned)i;
        }
    }
}

// ---- pass 5: per-bucket LDS counting sort -> rowptr + srcp + eap (clean writes)
__global__ __launch_bounds__(256) void bucketsort_kernel(
        const unsigned* __restrict__ sorted,
        const int* __restrict__ bbase, const int* __restrict__ btot,
        int* __restrict__ rowptr,
        const int* __restrict__ ei, const float* __restrict__ ea,
        int* __restrict__ srcp, __half* __restrict__ eap, int N, int E) {
    __shared__ int h[256];
    __shared__ int tmp[CAP];
    int b = blockIdx.x;
    int lo = b << 8;
    int s = bbase[b], cnt = btot[b];
    int tid = threadIdx.x;

    h[tid] = 0;
    __syncthreads();
    for (int i = tid; i < cnt; i += 256) atomicAdd(&h[sorted[s + i] >> 24], 1);
    __syncthreads();
    int v = h[tid];
    for (int off = 1; off < 256; off <<= 1) {
        int t = (tid >= off) ? h[tid - off] : 0;
        __syncthreads();
        h[tid] += t;
        __syncthreads();
    }
    int excl = h[tid] - v;
    int dst = lo + tid;
    if (dst < N) rowptr[dst] = s + excl;
    if (b == 0 && tid == 0) rowptr[N] = E;
    __syncthreads();
    h[tid] = excl;                  // per-dst cursor
    __syncthreads();
    for (int i = tid; i < cnt; i += 256) {
        unsigned p2 = sorted[s + i];
        int dl = p2 >> 24;
        int eid = p2 & 0xFFFFFF;
        int r = atomicAdd(&h[dl], 1);
        if (r < CAP) {
            tmp[r] = eid;
        } else {                    // overflow fallback (never for uniform input)
            int slot = s + r;
            srcp[slot] = ei[eid];
            float4 a0 = *(const float4*)(ea + (size_t)eid * 8);
            float4 a1 = *(const float4*)(ea + (size_t)eid * 8 + 4);
            uint4 u;
            u.x = F2H(a0.x, a0.y); u.y = F2H(a0.z, a0.w);
            u.z = F2H(a1.x, a1.y); u.w = F2H(a1.z, a1.w);
            *(uint4*)(eap + (size_t)slot * 8) = u;
        }
    }
    __syncthreads();
    int m = cnt < CAP ? cnt : CAP;
    for (int j = tid; j < m; j += 256) {
        int eid = tmp[j];
        int slot = s + j;
        srcp[slot] = ei[eid];
        float4 a0 = *(const float4*)(ea + (size_t)eid * 8);
        float4 a1 = *(const float4*)(ea + (size_t)eid * 8 + 4);
        uint4 u;
        u.x = F2H(a0.x, a0.y); u.y = F2H(a0.z, a0.w);
        u.z = F2H(a1.x, a1.y); u.w = F2H(a1.z, a1.w);
        *(uint4*)(eap + (size_t)slot * 8) = u;
    }
}

// ------- projections, H=8 layers: Q,S fp32 unpadded; KV fp16 packed -------
template<int CIN, int C, int PK>
__global__ void proj8_kernel(const float* __restrict__ X,
                             const float* __restrict__ wq, const float* __restrict__ bq,
                             const float* __restrict__ wk, const float* __restrict__ bk,
                             const float* __restrict__ wv, const float* __restrict__ bv,
                             const float* __restrict__ wsk, const float* __restrict__ bsk,
                             float* __restrict__ Q, __half* __restrict__ KV,
                             float* __restrict__ S, int N)
{
    const int HC = 8 * C;
    int idx = blockIdx.x * blockDim.x + threadIdx.x;
    if (idx >= N * HC) return;
    int n = idx / HC;
    int c = idx - n * HC;
    int h = c / C;
    int cc = c - h * C;
    float q = bq[c], k = bk[c], v = bv[c], s = bsk[c];
    const float* xr = X + (size_t)n * CIN;
#pragma unroll
    for (int i = 0; i < CIN; ++i) {
        float xi = xr[i];
        q = fmaf(xi, wq[i * HC + c], q);
        k = fmaf(xi, wk[i * HC + c], k);
        v = fmaf(xi, wv[i * HC + c], v);
        s = fmaf(xi, wsk[i * HC + c], s);
    }
    Q[(size_t)n * HC + c] = q;
    __half* kp = KV + (size_t)n * (8 * PK) + h * PK;
    kp[cc] = __float2half_rn(k);
    kp[C + cc] = __float2half_rn(v);
    S[(size_t)n * HC + c] = s;
}

// ------- projection, layer3: Q,S fp32; K,V fp16 rows of 64 -------
__global__ void proj64_kernel(const float* __restrict__ X,
                              const float* __restrict__ wq, const float* __restrict__ bq,
                              const float* __restrict__ wk, const float* __restrict__ bk,
                              const float* __restrict__ wv, const float* __restrict__ bv,
                              const float* __restrict__ wsk, const float* __restrict__ bsk,
                              float* __restrict__ Q, __half* __restrict__ K16,
                              __half* __restrict__ V16, float* __restrict__ S, int N)
{
    int idx = blockIdx.x * blockDim.x + threadIdx.x;
    if (idx >= N * 64) return;
    int n = idx >> 6;
    int c = idx & 63;
    float q = bq[c], k = bk[c], v = bv[c], s = bsk[c];
    const float* xr = X + (size_t)n * 24;
#pragma unroll
    for (int i = 0; i < 24; ++i) {
        float xi = xr[i];
        q = fmaf(xi, wq[i * 64 + c], q);
        k = fmaf(xi, wk[i * 64 + c], k);
        v = fmaf(xi, wv[i * 64 + c], v);
        s = fmaf(xi, wsk[i * 64 + c], s);
    }
    Q[idx] = q;
    K16[idx] = __float2half_rn(k);
    V16[idx] = __float2half_rn(v);
    S[idx] = s;
}

// ---- fused gather+gate, H=8: thread per (node, head), factorized e -----
template<int C, int PK>
__global__ void gather8f_kernel(const int* __restrict__ rowptr,
                                const int* __restrict__ srcp,
                                const __half* __restrict__ eap,
                                const float* __restrict__ we,
                                const float* __restrict__ Q,
                                const __half* __restrict__ KV,
                                const float* __restrict__ S,
                                const float* __restrict__ wb,
                                float* __restrict__ OUT,
                                int N, float scale)
{
    const int HC = 8 * C;
    int tid = blockIdx.x * blockDim.x + threadIdx.x;
    int n = tid >> 3;
    int h = tid & 7;
    if (n >= N) return;

    float q[C];
    const float* Qp = Q + (size_t)n * HC + h * C;
#pragma unroll
    for (int c = 0; c < C; ++c) q[c] = Qp[c];

    float qe[8];
#pragma unroll
    for (int d = 0; d < 8; ++d) {
        float t = 0.f;
#pragma unroll
        for (int c = 0; c < C; ++c) t = fmaf(we[d * HC + h * C + c], q[c], t);
        qe[d] = t;
    }

    float num[C];
#pragma unroll
    for (int c = 0; c < C; ++c) num[c] = 0.f;
    float sacc[8];
#pragma unroll
    for (int d = 0; d < 8; ++d) sacc[d] = 0.f;
    float den = 0.f;

    int rs = rowptr[n], re = rowptr[n + 1];
    int j = rs;
    for (; j + 1 < re; j += 2) {
        int s0 = srcp[j], s1 = srcp[j + 1];
        float a0[8], a1[8];
        loadA(eap + (size_t)j * 8, a0);
        loadA(eap + (size_t)(j + 1) * 8, a1);
        float k0[C], v0[C], k1[C], v1[C];
        loadKV<C>(KV + (size_t)s0 * (8 * PK) + h * PK, k0, v0);
        loadKV<C>(KV + (size_t)s1 * (8 * PK) + h * PK, k1, v1);
        float d0 = 0.f, d1 = 0.f;
#pragma unroll
        for (int c = 0; c < C; ++c) {
            d0 = fmaf(q[c], k0[c], d0);
            d1 = fmaf(q[c], k1[c], d1);
        }
        float qa0 = 0.f, qa1 = 0.f;
#pragma unroll
        for (int d = 0; d < 8; ++d) {
            qa0 = fmaf(qe[d], a0[d], qa0);
            qa1 = fmaf(qe[d], a1[d], qa1);
        }
        float ex0 = __expf((d0 + qa0) * scale);
        float ex1 = __expf((d1 + qa1) * scale);
        den += ex0 + ex1;
#pragma unroll
        for (int c = 0; c < C; ++c) {
            num[c] = fmaf(ex0, v0[c], num[c]);
            num[c] = fmaf(ex1, v1[c], num[c]);
        }
#pragma unroll
        for (int d = 0; d < 8; ++d)
            sacc[d] = fmaf(ex0, a0[d], fmaf(ex1, a1[d], sacc[d]));
    }
    if (j < re) {
        int s0 = srcp[j];
        float a0[8];
        loadA(eap + (size_t)j * 8, a0);
        float k0[C], v0[C];
        loadKV<C>(KV + (size_t)s0 * (8 * PK) + h * PK, k0, v0);
        float d0 = 0.f;
#pragma unroll
        for (int c = 0; c < C; ++c) d0 = fmaf(q[c], k0[c], d0);
        float qa0 = 0.f;
#pragma unroll
        for (int d = 0; d < 8; ++d) qa0 = fmaf(qe[d], a0[d], qa0);
        float ex0 = __expf((d0 + qa0) * scale);
        den += ex0;
#pragma unroll
        for (int c = 0; c < C; ++c) num[c] = fmaf(ex0, v0[c], num[c]);
#pragma unroll
        for (int d = 0; d < 8; ++d) sacc[d] = fmaf(ex0, a0[d], sacc[d]);
    }

    float inv = 1.f / (den + 1e-16f);
    float outc[C], sc[C];
    float gd = 0.f;
#pragma unroll
    for (int c = 0; c < C; ++c) {
        float e_ = 0.f;
#pragma unroll
        for (int d = 0; d < 8; ++d) e_ = fmaf(we[d * HC + h * C + c], sacc[d], e_);
        float o = (num[c] + e_) * inv;
        float s_ = S[(size_t)n * HC + h * C + c];
        outc[c] = o;
        sc[c] = s_;
        gd += o * wb[h * C + c] + s_ * wb[HC + h * C + c] + (o - s_) * wb[2 * HC + h * C + c];
    }
    gd += __shfl_xor(gd, 1, 8);
    gd += __shfl_xor(gd, 2, 8);
    gd += __shfl_xor(gd, 4, 8);
    float g = 1.f / (1.f + __expf(-gd));
#pragma unroll
    for (int c = 0; c < C; ++c) {
        float hh = fmaxf(g * sc[c] + (1.f - g) * outc[c], 0.f);
        OUT[(size_t)n * HC + h * C + c] = hh;
    }
}

// ---- fused gather+gate+classifier, H=1,C=64: 16 lanes/node, factorized ----
__global__ void gather64f_kernel(const int* __restrict__ rowptr,
                                 const int* __restrict__ srcp,
                                 const __half* __restrict__ eap,
                                 const float* __restrict__ we,
                                 const float* __restrict__ Q,
                                 const __half* __restrict__ K16,
                                 const __half* __restrict__ V16,
                                 const float* __restrict__ S,
                                 const float* __restrict__ wb,
                                 const float* __restrict__ wc,
                                 const float* __restrict__ bc,
                                 float* __restrict__ OUT,
                                 int N, float scale)
{
    int grp = (blockIdx.x * blockDim.x + threadIdx.x) >> 4;   // node
    int l16 = threadIdx.x & 15;
    if (grp >= N) return;
    int c0 = l16 << 2;

    float wv[8][4];
#pragma unroll
    for (int d = 0; d < 8; ++d) *(float4*)wv[d] = *(const float4*)(we + d * 64 + c0);
    float4 qv = *(const float4*)(Q + (size_t)grp * 64 + c0);
    float qe[8];
#pragma unroll
    for (int d = 0; d < 8; ++d) {
        float t = wv[d][0] * qv.x;
        t = fmaf(wv[d][1], qv.y, t);
        t = fmaf(wv[d][2], qv.z, t);
        t = fmaf(wv[d][3], qv.w, t);
        qe[d] = t;
    }

    float num0 = 0.f, num1 = 0.f, num2 = 0.f, num3 = 0.f, den = 0.f;
    float sacc[8];
#pragma unroll
    for (int d = 0; d < 8; ++d) sacc[d] = 0.f;

    int rs = rowptr[grp], re = rowptr[grp + 1];
    int j = rs;
    for (; j + 1 < re; j += 2) {
        int s0 = srcp[j], s1 = srcp[j + 1];
        float a0[8], a1[8];
        loadA(eap + (size_t)j * 8, a0);
        loadA(eap + (size_t)(j + 1) * 8, a1);
        uint2 ku0 = *(const uint2*)(K16 + (size_t)s0 * 64 + c0);
        uint2 vu0 = *(const uint2*)(V16 + (size_t)s0 * 64 + c0);
        uint2 ku1 = *(const uint2*)(K16 + (size_t)s1 * 64 + c0);
        uint2 vu1 = *(const uint2*)(V16 + (size_t)s1 * 64 + c0);
        float2 ka0 = H2F(ku0.x), kb0 = H2F(ku0.y);
        float2 va0 = H2F(vu0.x), vb0 = H2F(vu0.y);
        float2 ka1 = H2F(ku1.x), kb1 = H2F(ku1.y);
        float2 va1 = H2F(vu1.x), vb1 = H2F(vu1.y);
        float t0 = qv.x * ka0.x;
        t0 = fmaf(qv.y, ka0.y, t0); t0 = fmaf(qv.z, kb0.x, t0); t0 = fmaf(qv.w, kb0.y, t0);
        float t1 = qv.x * ka1.x;
        t1 = fmaf(qv.y, ka1.y, t1); t1 = fmaf(qv.z, kb1.x, t1); t1 = fmaf(qv.w, kb1.y, t1);
#pragma unroll
        for (int d = 0; d < 8; ++d) {
            t0 = fmaf(qe[d], a0[d], t0);
            t1 = fmaf(qe[d], a1[d], t1);
        }
#pragma unroll
        for (int off = 8; off > 0; off >>= 1) {
            t0 += __shfl_xor(t0, off, 16);
            t1 += __shfl_xor(t1, off, 16);
        }
        float ex0 = __expf(t0 * scale);
        float ex1 = __expf(t1 * scale);
        den += ex0 + ex1;
        num0 = fmaf(ex0, va0.x, fmaf(ex1, va1.x, num0));
        num1 = fmaf(ex0, va0.y, fmaf(ex1, va1.y, num1));
        num2 = fmaf(ex0, vb0.x, fmaf(ex1, vb1.x, num2));
        num3 = fmaf(ex0, vb0.y, fmaf(ex1, vb1.y, num3));
#pragma unroll
        for (int d = 0; d < 8; ++d)
            sacc[d] = fmaf(ex0, a0[d], fmaf(ex1, a1[d], sacc[d]));
    }
    if (j < re) {
        int s0 = srcp[j];
        float a0[8];
        loadA(eap + (size_t)j * 8, a0);
        uint2 ku0 = *(const uint2*)(K16 + (size_t)s0 * 64 + c0);
        uint2 vu0 = *(const uint2*)(V16 + (size_t)s0 * 64 + c0);
        float2 ka0 = H2F(ku0.x), kb0 = H2F(ku0.y);
        float2 va0 = H2F(vu0.x), vb0 = H2F(vu0.y);
        float t0 = qv.x * ka0.x;
        t0 = fmaf(qv.y, ka0.y, t0); t0 = fmaf(qv.z, kb0.x, t0); t0 = fmaf(qv.w, kb0.y, t0);
#pragma unroll
        for (int d = 0; d < 8; ++d) t0 = fmaf(qe[d], a0[d], t0);
#pragma unroll
        for (int off = 8; off > 0; off >>= 1) t0 += __shfl_xor(t0, off, 16);
        float ex0 = __expf(t0 * scale);
        den += ex0;
        num0 = fmaf(ex0, va0.x, num0);
        num1 = fmaf(ex0, va0.y, num1);
        num2 = fmaf(ex0, vb0.x, num2);
        num3 = fmaf(ex0, vb0.y, num3);
#pragma unroll
        for (int d = 0; d < 8; ++d) sacc[d] = fmaf(ex0, a0[d], sacc[d]);
    }

#pragma unroll
    for (int d = 0; d < 8; ++d) {
        num0 = fmaf(wv[d][0], sacc[d], num0);
        num1 = fmaf(wv[d][1], sacc[d], num1);
        num2 = fmaf(wv[d][2], sacc[d], num2);
        num3 = fmaf(wv[d][3], sacc[d], num3);
    }
    float inv = 1.f / (den + 1e-16f);
    float o0 = num0 * inv, o1 = num1 * inv, o2 = num2 * inv, o3 = num3 * inv;
    float4 sv  = *(const float4*)(S + (size_t)grp * 64 + c0);
    float4 wb0 = *(const float4*)(wb + c0);
    float4 wb1 = *(const float4*)(wb + 64 + c0);
    float4 wb2 = *(const float4*)(wb + 128 + c0);
    float gd = o0 * wb0.x + sv.x * wb1.x + (o0 - sv.x) * wb2.x;
    gd += o1 * wb0.y + sv.y * wb1.y + (o1 - sv.y) * wb2.y;
    gd += o2 * wb0.z + sv.z * wb1.z + (o2 - sv.z) * wb2.z;
    gd += o3 * wb0.w + sv.w * wb1.w + (o3 - sv.w) * wb2.w;
#pragma unroll
    for (int off = 8; off > 0; off >>= 1) gd += __shfl_xor(gd, off, 16);
    float g = 1.f / (1.f + __expf(-gd));
    float h0 = fmaxf(g * sv.x + (1.f - g) * o0, 0.f);
    float h1 = fmaxf(g * sv.y + (1.f - g) * o1, 0.f);
    float h2 = fmaxf(g * sv.z + (1.f - g) * o2, 0.f);
    float h3 = fmaxf(g * sv.w + (1.f - g) * o3, 0.f);
    float4 wcv = *(const float4*)(wc + c0);
    float t = h0 * wcv.x + h1 * wcv.y + h2 * wcv.z + h3 * wcv.w;
#pragma unroll
    for (int off = 8; off > 0; off >>= 1) t += __shfl_xor(t, off, 16);
    if (l16 == 0) OUT[grp] = t + bc[0];
}

extern "C" void kernel_launch(void* const* d_in, const int* in_sizes, int n_in,
                              void* d_out, int out_size, void* d_ws, size_t ws_size,
                              hipStream_t stream) {
    const float* x  = (const float*)d_in[0];
    const int*   ei = (const int*)d_in[1];
    const float* ea = (const float*)d_in[2];
    const int N = in_sizes[0] / 32;
    const int E = in_sizes[1] / 2;

    int p = 3;
    const float *wq1=(const float*)d_in[p+0], *bq1=(const float*)d_in[p+1],
                *wk1=(const float*)d_in[p+2], *bk1=(const float*)d_in[p+3],
                *wv1=(const float*)d_in[p+4], *bv1=(const float*)d_in[p+5],
                *we1=(const float*)d_in[p+6],
                *wsk1=(const float*)d_in[p+7], *bsk1=(const float*)d_in[p+8],
                *wb1=(const float*)d_in[p+9];
    p += 10;
    const float *wq2=(const float*)d_in[p+0], *bq2=(const float*)d_in[p+1],
                *wk2=(const float*)d_in[p+2], *bk2=(const float*)d_in[p+3],
                *wv2=(const float*)d_in[p+4], *bv2=(const float*)d_in[p+5],
                *we2=(const float*)d_in[p+6],
                *wsk2=(const float*)d_in[p+7], *bsk2=(const float*)d_in[p+8],
                *wb2=(const float*)d_in[p+9];
    p += 10;
    const float *wq3=(const float*)d_in[p+0], *bq3=(const float*)d_in[p+1],
                *wk3=(const float*)d_in[p+2], *bk3=(const float*)d_in[p+3],
                *wv3=(const float*)d_in[p+4], *bv3=(const float*)d_in[p+5],
                *we3=(const float*)d_in[p+6],
                *wsk3=(const float*)d_in[p+7], *bsk3=(const float*)d_in[p+8],
                *wb3=(const float*)d_in[p+9];
    p += 10;
    const float *wc = (const float*)d_in[p+0], *bc = (const float*)d_in[p+1];

    float* out = (float*)d_out;

    // ---- workspace layout ----
    float* ws = (float*)d_ws;
    float* Hb = ws;                               // N*48 fp32
    float* Qb = Hb + (size_t)N * 48;              // N*64 fp32
    float* Sb = Qb + (size_t)N * 64;              // N*64 fp32
    __half* KV16  = (__half*)(Sb + (size_t)N * 64);  // N*128 halfs
    __half* K3    = KV16;
    __half* V3    = KV16 + (size_t)N * 64;
    __half* eap16 = KV16 + (size_t)N * 128;       // E*8 halfs
    int* ip      = (int*)(eap16 + (size_t)E * 8);
    int* rowptr  = ip;                 // N+2
    int* btot    = rowptr + (N + 2);   // 512
    int* bbase   = btot + 512;         // 512
    int* srcp    = bbase + 512;        // E
    int* hist    = srcp + E;           // NBUCK * nblkR
    // sorted aliases Qb (consumed by bucketsort before proj writes Qb)
    unsigned* sorted = (unsigned*)Qb;  // E * 4B <= N*64*4B

    const int BLK = 256;
    const int nblkR = (E + RCHUNK - 1) / RCHUNK;       // <= 1024
    const int nbuckUsed = (N + 255) >> 8;              // buckets covering dst range

    // ---------------- radix bucket + LDS counting sort ----------------
    histA_kernel<<<nblkR, 256, 0, stream>>>(ei, hist, E, nblkR);
    scanB_kernel<<<NBUCK, 1024, 0, stream>>>(hist, btot, nblkR);
    scanC_kernel<<<1, NBUCK, 0, stream>>>(btot, bbase);
    reorderB_kernel<<<nblkR, 256, 0, stream>>>(ei, hist, bbase, sorted, E, nblkR);
    bucketsort_kernel<<<nbuckUsed, 256, 0, stream>>>(
        sorted, bbase, btot, rowptr, ei, ea, srcp, eap16, N, E);

    // ------- layer 1: cin=32, H=8, C=6 (PK=16) -------
    proj8_kernel<32,6,16><<<(N*48 + BLK-1)/BLK, BLK, 0, stream>>>(
        x, wq1,bq1, wk1,bk1, wv1,bv1, wsk1,bsk1, Qb, KV16, Sb, N);
    gather8f_kernel<6,16><<<(N*8 + BLK-1)/BLK, BLK, 0, stream>>>(
        rowptr, srcp, eap16, we1, Qb, KV16, Sb, wb1, Hb, N, 1.0f/sqrtf(6.0f));

    // ------- layer 2: cin=48, H=8, C=3 (PK=8) -------
    proj8_kernel<48,3,8><<<(N*24 + BLK-1)/BLK, BLK, 0, stream>>>(
        Hb, wq2,bq2, wk2,bk2, wv2,bv2, wsk2,bsk2, Qb, KV16, Sb, N);
    gather8f_kernel<3,8><<<(N*8 + BLK-1)/BLK, BLK, 0, stream>>>(
        rowptr, srcp, eap16, we2, Qb, KV16, Sb, wb2, Hb, N, 1.0f/sqrtf(3.0f));

    // ------- layer 3: cin=24, H=1, C=64 -------
    proj64_kernel<<<(N*64 + BLK-1)/BLK, BLK, 0, stream>>>(
        Hb, wq3,bq3, wk3,bk3, wv3,bv3, wsk3,bsk3, Qb, K3, V3, Sb, N);
    gather64f_kernel<<<((size_t)N*16 + BLK-1)/BLK, BLK, 0, stream>>>(
        rowptr, srcp, eap16, we3, Qb, K3, V3, Sb, wb3, wc, bc, out, N, 1.0f/8.0f);
}

// Round 11
// 809.719 us; speedup vs baseline: 2.6811x; 1.0114x over previous
//
#include <hip/hip_runtime.h>
#include <hip/hip_fp16.h>
#include <math.h>

#define RCHUNK 8192            // edges per radix block
#define NBUCK 512              // max radix buckets (bucket = 256 dst)
#define CAP 12288              // LDS tmp capacity per bucket

__device__ __forceinline__ float2 H2F(unsigned u) {
    __half2 h = *reinterpret_cast<__half2*>(&u);
    return __half22float2(h);
}
__device__ __forceinline__ unsigned F2H(float a, float b) {
    __half2 h = __floats2half2_rn(a, b);
    return *reinterpret_cast<unsigned*>(&h);
}

// unpack 8 fp16 edge attrs
__device__ __forceinline__ void loadA(const __half* p, float* a) {
    uint4 u = *(const uint4*)p;
    float2 t;
    t = H2F(u.x); a[0] = t.x; a[1] = t.y;
    t = H2F(u.y); a[2] = t.x; a[3] = t.y;
    t = H2F(u.z); a[4] = t.x; a[5] = t.y;
    t = H2F(u.w); a[6] = t.x; a[7] = t.y;
}

// packed per-head K/V fp16 packet
template<int C>
__device__ __forceinline__ void loadKV(const __half* p, float* k, float* v) {
    if constexpr (C == 6) {
        uint4 p0 = *(const uint4*)p;
        uint4 p1 = *(const uint4*)(p + 8);
        float2 t;
        t = H2F(p0.x); k[0] = t.x; k[1] = t.y;
        t = H2F(p0.y); k[2] = t.x; k[3] = t.y;
        t = H2F(p0.z); k[4] = t.x; k[5] = t.y;
        t = H2F(p0.w); v[0] = t.x; v[1] = t.y;
        t = H2F(p1.x); v[2] = t.x; v[3] = t.y;
        t = H2F(p1.y); v[4] = t.x; v[5] = t.y;
    } else {  // C == 3
        uint4 p0 = *(const uint4*)p;
        float2 t;
        t = H2F(p0.x); k[0] = t.x; k[1] = t.y;
        t = H2F(p0.y); k[2] = t.x; v[0] = t.y;
        t = H2F(p0.z); v[1] = t.x; v[2] = t.y;
    }
}

// ---- pass 1: per-block histogram over 512 buckets (LDS atomics only) ----
__global__ void histA_kernel(const int* __restrict__ ei, int* __restrict__ hist,
                             int E, int nblk) {
    __shared__ int h[NBUCK];
    h[threadIdx.x] = 0;
    h[threadIdx.x + 256] = 0;
    __syncthreads();
    int base = blockIdx.x * RCHUNK;
#pragma unroll
    for (int r = 0; r < RCHUNK / 256; ++r) {
        int i = base + r * 256 + threadIdx.x;
        if (i < E) atomicAdd(&h[ei[E + i] >> 8], 1);
    }
    __syncthreads();
    hist[threadIdx.x * nblk + blockIdx.x] = h[threadIdx.x];
    hist[(threadIdx.x + 256) * nblk + blockIdx.x] = h[threadIdx.x + 256];
}

// ---- pass 2: per-bucket exclusive scan over blocks; total -> btot ----
__global__ void scanB_kernel(int* __restrict__ hist, int* __restrict__ btot, int nblk) {
    __shared__ int sm[1024];
    int b = blockIdx.x;
    int tid = threadIdx.x;
    int v = (tid < nblk) ? hist[b * nblk + tid] : 0;
    sm[tid] = v;
    __syncthreads();
    for (int off = 1; off < 1024; off <<= 1) {
        int t = (tid >= off) ? sm[tid - off] : 0;
        __syncthreads();
        sm[tid] += t;
        __syncthreads();
    }
    if (tid < nblk) hist[b * nblk + tid] = sm[tid] - v;   // exclusive
    if (tid == 1023) btot[b] = sm[1023];
}

// ---- pass 3: exclusive scan of bucket totals -> bbase ----
__global__ void scanC_kernel(const int* __restrict__ btot, int* __restrict__ bbase) {
    __shared__ int sm[NBUCK];
    int tid = threadIdx.x;
    int v = btot[tid];
    sm[tid] = v;
    __syncthreads();
    for (int off = 1; off < NBUCK; off <<= 1) {
        int t = (tid >= off) ? sm[tid - off] : 0;
        __syncthreads();
        sm[tid] += t;
        __syncthreads();
    }
    bbase[tid] = sm[tid] - v;
}

// ---- pass 4: reorder packed (dstlo<<24 | eid) into bucket-grouped array ----
__global__ void reorderB_kernel(const int* __restrict__ ei, const int* __restrict__ hist,
                                const int* __restrict__ bbase, unsigned* __restrict__ sorted,
                                int E, int nblk) {
    __shared__ int off[NBUCK];
    off[threadIdx.x] = bbase[threadIdx.x] + hist[threadIdx.x * nblk + blockIdx.x];
    off[threadIdx.x + 256] = bbase[threadIdx.x + 256] + hist[(threadIdx.x + 256) * nblk + blockIdx.x];
    __syncthreads();
    int base = blockIdx.x * RCHUNK;
#pragma unroll
    for (int r = 0; r < RCHUNK / 256; ++r) {
        int i = base + r * 256 + threadIdx.x;
        if (i < E) {
            int dst = ei[E + i];
            int k = atomicAdd(&off[dst >> 8], 1);
            sorted[k] = ((unsigned)(dst & 255) << 24) | (unsigned)i;
        }
    }
}

// ---- pass 5: per-bucket LDS counting sort -> rowptr + srcp + eap ----
__global__ __launch_bounds__(256) void bucketsort_kernel(
        const unsigned* __restrict__ sorted,
        const int* __restrict__ bbase, const int* __restrict__ btot,
        int* __restrict__ rowptr,
        const int* __restrict__ ei, const float* __restrict__ ea,
        int* __restrict__ srcp, __half* __restrict__ eap, int N, int E) {
    __shared__ int h[256];
    __shared__ int tmp[CAP];
    int b = blockIdx.x;
    int lo = b << 8;
    int s = bbase[b], cnt = btot[b];
    int tid = threadIdx.x;

    h[tid] = 0;
    __syncthreads();
    for (int i = tid; i < cnt; i += 256) atomicAdd(&h[sorted[s + i] >> 24], 1);
    __syncthreads();
    int v = h[tid];
    for (int off = 1; off < 256; off <<= 1) {
        int t = (tid >= off) ? h[tid - off] : 0;
        __syncthreads();
        h[tid] += t;
        __syncthreads();
    }
    int excl = h[tid] - v;
    int dst = lo + tid;
    if (dst < N) rowptr[dst] = s + excl;
    if (b == 0 && tid == 0) rowptr[N] = E;
    __syncthreads();
    h[tid] = excl;
    __syncthreads();
    for (int i = tid; i < cnt; i += 256) {
        unsigned p2 = sorted[s + i];
        int dl = p2 >> 24;
        int eid = p2 & 0xFFFFFF;
        int r = atomicAdd(&h[dl], 1);
        if (r < CAP) {
            tmp[r] = eid;
        } else {
            int slot = s + r;
            srcp[slot] = ei[eid];
            float4 a0 = *(const float4*)(ea + (size_t)eid * 8);
            float4 a1 = *(const float4*)(ea + (size_t)eid * 8 + 4);
            uint4 u;
            u.x = F2H(a0.x, a0.y); u.y = F2H(a0.z, a0.w);
            u.z = F2H(a1.x, a1.y); u.w = F2H(a1.z, a1.w);
            *(uint4*)(eap + (size_t)slot * 8) = u;
        }
    }
    __syncthreads();
    int m = cnt < CAP ? cnt : CAP;
    for (int j = tid; j < m; j += 256) {
        int eid = tmp[j];
        int slot = s + j;
        srcp[slot] = ei[eid];
        float4 a0 = *(const float4*)(ea + (size_t)eid * 8);
        float4 a1 = *(const float4*)(ea + (size_t)eid * 8 + 4);
        uint4 u;
        u.x = F2H(a0.x, a0.y); u.y = F2H(a0.z, a0.w);
        u.z = F2H(a1.x, a1.y); u.w = F2H(a1.z, a1.w);
        *(uint4*)(eap + (size_t)slot * 8) = u;
    }
}

// ------- projections, H=8 layers -------
template<int CIN, int C, int PK>
__global__ void proj8_kernel(const float* __restrict__ X,
                             const float* __restrict__ wq, const float* __restrict__ bq,
                             const float* __restrict__ wk, const float* __restrict__ bk,
                             const float* __restrict__ wv, const float* __restrict__ bv,
                             const float* __restrict__ wsk, const float* __restrict__ bsk,
                             float* __restrict__ Q, __half* __restrict__ KV,
                             float* __restrict__ S, int N)
{
    const int HC = 8 * C;
    int idx = blockIdx.x * blockDim.x + threadIdx.x;
    if (idx >= N * HC) return;
    int n = idx / HC;
    int c = idx - n * HC;
    int h = c / C;
    int cc = c - h * C;
    float q = bq[c], k = bk[c], v = bv[c], s = bsk[c];
    const float* xr = X + (size_t)n * CIN;
#pragma unroll
    for (int i = 0; i < CIN; ++i) {
        float xi = xr[i];
        q = fmaf(xi, wq[i * HC + c], q);
        k = fmaf(xi, wk[i * HC + c], k);
        v = fmaf(xi, wv[i * HC + c], v);
        s = fmaf(xi, wsk[i * HC + c], s);
    }
    Q[(size_t)n * HC + c] = q;
    __half* kp = KV + (size_t)n * (8 * PK) + h * PK;
    kp[cc] = __float2half_rn(k);
    kp[C + cc] = __float2half_rn(v);
    S[(size_t)n * HC + c] = s;
}

// ------- projection, layer3 -------
__global__ void proj64_kernel(const float* __restrict__ X,
                              const float* __restrict__ wq, const float* __restrict__ bq,
                              const float* __restrict__ wk, const float* __restrict__ bk,
                              const float* __restrict__ wv, const float* __restrict__ bv,
                              const float* __restrict__ wsk, const float* __restrict__ bsk,
                              float* __restrict__ Q, __half* __restrict__ K16,
                              __half* __restrict__ V16, float* __restrict__ S, int N)
{
    int idx = blockIdx.x * blockDim.x + threadIdx.x;
    if (idx >= N * 64) return;
    int n = idx >> 6;
    int c = idx & 63;
    float q = bq[c], k = bk[c], v = bv[c], s = bsk[c];
    const float* xr = X + (size_t)n * 24;
#pragma unroll
    for (int i = 0; i < 24; ++i) {
        float xi = xr[i];
        q = fmaf(xi, wq[i * 64 + c], q);
        k = fmaf(xi, wk[i * 64 + c], k);
        v = fmaf(xi, wv[i * 64 + c], v);
        s = fmaf(xi, wsk[i * 64 + c], s);
    }
    Q[idx] = q;
    K16[idx] = __float2half_rn(k);
    V16[idx] = __float2half_rn(v);
    S[idx] = s;
}

// ---- fused gather+gate, H=8: thread per (node, head); UNROLL=2 or 4 ----
template<int C, int PK, int UNR>
__global__ void gather8f_kernel(const int* __restrict__ rowptr,
                                const int* __restrict__ srcp,
                                const __half* __restrict__ eap,
                                const float* __restrict__ we,
                                const float* __restrict__ Q,
                                const __half* __restrict__ KV,
                                const float* __restrict__ S,
                                const float* __restrict__ wb,
                                float* __restrict__ OUT,
                                int N, float scale)
{
    const int HC = 8 * C;
    int tid = blockIdx.x * blockDim.x + threadIdx.x;
    int n = tid >> 3;
    int h = tid & 7;
    if (n >= N) return;

    float q[C];
    const float* Qp = Q + (size_t)n * HC + h * C;
#pragma unroll
    for (int c = 0; c < C; ++c) q[c] = Qp[c];

    float qe[8];
#pragma unroll
    for (int d = 0; d < 8; ++d) {
        float t = 0.f;
#pragma unroll
        for (int c = 0; c < C; ++c) t = fmaf(we[d * HC + h * C + c], q[c], t);
        qe[d] = t;
    }

    float num[C];
#pragma unroll
    for (int c = 0; c < C; ++c) num[c] = 0.f;
    float sacc[8];
#pragma unroll
    for (int d = 0; d < 8; ++d) sacc[d] = 0.f;
    float den = 0.f;

    int rs = rowptr[n], re = rowptr[n + 1];
    int j = rs;
    for (; j + UNR - 1 < re; j += UNR) {
        int se[UNR];
        float a[UNR][8], kk[UNR][C], vv[UNR][C];
#pragma unroll
        for (int u = 0; u < UNR; ++u) se[u] = srcp[j + u];
#pragma unroll
        for (int u = 0; u < UNR; ++u) loadA(eap + (size_t)(j + u) * 8, a[u]);
#pragma unroll
        for (int u = 0; u < UNR; ++u)
            loadKV<C>(KV + (size_t)se[u] * (8 * PK) + h * PK, kk[u], vv[u]);
        float ex[UNR];
#pragma unroll
        for (int u = 0; u < UNR; ++u) {
            float d0 = 0.f;
#pragma unroll
            for (int c = 0; c < C; ++c) d0 = fmaf(q[c], kk[u][c], d0);
            float qa = 0.f;
#pragma unroll
            for (int d = 0; d < 8; ++d) qa = fmaf(qe[d], a[u][d], qa);
            ex[u] = __expf((d0 + qa) * scale);
        }
#pragma unroll
        for (int u = 0; u < UNR; ++u) {
            den += ex[u];
#pragma unroll
            for (int c = 0; c < C; ++c) num[c] = fmaf(ex[u], vv[u][c], num[c]);
#pragma unroll
            for (int d = 0; d < 8; ++d) sacc[d] = fmaf(ex[u], a[u][d], sacc[d]);
        }
    }
    for (; j < re; ++j) {
        int s0 = srcp[j];
        float a0[8];
        loadA(eap + (size_t)j * 8, a0);
        float k0[C], v0[C];
        loadKV<C>(KV + (size_t)s0 * (8 * PK) + h * PK, k0, v0);
        float d0 = 0.f;
#pragma unroll
        for (int c = 0; c < C; ++c) d0 = fmaf(q[c], k0[c], d0);
        float qa0 = 0.f;
#pragma unroll
        for (int d = 0; d < 8; ++d) qa0 = fmaf(qe[d], a0[d], qa0);
        float ex0 = __expf((d0 + qa0) * scale);
        den += ex0;
#pragma unroll
        for (int c = 0; c < C; ++c) num[c] = fmaf(ex0, v0[c], num[c]);
#pragma unroll
        for (int d = 0; d < 8; ++d) sacc[d] = fmaf(ex0, a0[d], sacc[d]);
    }

    float inv = 1.f / (den + 1e-16f);
    float outc[C], sc[C];
    float gd = 0.f;
#pragma unroll
    for (int c = 0; c < C; ++c) {
        float e_ = 0.f;
#pragma unroll
        for (int d = 0; d < 8; ++d) e_ = fmaf(we[d * HC + h * C + c], sacc[d], e_);
        float o = (num[c] + e_) * inv;
        float s_ = S[(size_t)n * HC + h * C + c];
        outc[c] = o;
        sc[c] = s_;
        gd += o * wb[h * C + c] + s_ * wb[HC + h * C + c] + (o - s_) * wb[2 * HC + h * C + c];
    }
    gd += __shfl_xor(gd, 1, 8);
    gd += __shfl_xor(gd, 2, 8);
    gd += __shfl_xor(gd, 4, 8);
    float g = 1.f / (1.f + __expf(-gd));
#pragma unroll
    for (int c = 0; c < C; ++c) {
        float hh = fmaxf(g * sc[c] + (1.f - g) * outc[c], 0.f);
        OUT[(size_t)n * HC + h * C + c] = hh;
    }
}

// ---- fused gather+gate+classifier, H=1,C=64: 16 lanes/node, 4-edge unroll ----
__global__ void gather64f_kernel(const int* __restrict__ rowptr,
                                 const int* __restrict__ srcp,
                                 const __half* __restrict__ eap,
                                 const float* __restrict__ we,
                                 const float* __restrict__ Q,
                                 const __half* __restrict__ K16,
                                 const __half* __restrict__ V16,
                                 const float* __restrict__ S,
                                 const float* __restrict__ wb,
                                 const float* __restrict__ wc,
                                 const float* __restrict__ bc,
                                 float* __restrict__ OUT,
                                 int N, float scale)
{
    int grp = (blockIdx.x * blockDim.x + threadIdx.x) >> 4;   // node
    int l16 = threadIdx.x & 15;
    if (grp >= N) return;
    int c0 = l16 << 2;

    float4 qv = *(const float4*)(Q + (size_t)grp * 64 + c0);
    // qe from we (wv not kept live through the loop)
    float qe[8];
#pragma unroll
    for (int d = 0; d < 8; ++d) {
        float4 w4 = *(const float4*)(we + d * 64 + c0);
        float t = w4.x * qv.x;
        t = fmaf(w4.y, qv.y, t);
        t = fmaf(w4.z, qv.z, t);
        t = fmaf(w4.w, qv.w, t);
        qe[d] = t;
    }

    float num0 = 0.f, num1 = 0.f, num2 = 0.f, num3 = 0.f, den = 0.f;
    float sacc[8];
#pragma unroll
    for (int d = 0; d < 8; ++d) sacc[d] = 0.f;

    int rs = rowptr[grp], re = rowptr[grp + 1];
    int j = rs;
    for (; j + 3 < re; j += 4) {
        int se[4];
        float a[4][8];
        uint2 ku[4], vu[4];
#pragma unroll
        for (int u = 0; u < 4; ++u) se[u] = srcp[j + u];
#pragma unroll
        for (int u = 0; u < 4; ++u) loadA(eap + (size_t)(j + u) * 8, a[u]);
#pragma unroll
        for (int u = 0; u < 4; ++u) {
            ku[u] = *(const uint2*)(K16 + (size_t)se[u] * 64 + c0);
            vu[u] = *(const uint2*)(V16 + (size_t)se[u] * 64 + c0);
        }
        float t[4];
#pragma unroll
        for (int u = 0; u < 4; ++u) {
            float2 ka = H2F(ku[u].x), kb = H2F(ku[u].y);
            float tt = qv.x * ka.x;
            tt = fmaf(qv.y, ka.y, tt); tt = fmaf(qv.z, kb.x, tt); tt = fmaf(qv.w, kb.y, tt);
#pragma unroll
            for (int d = 0; d < 8; ++d) tt = fmaf(qe[d], a[u][d], tt);
            t[u] = tt;
        }
#pragma unroll
        for (int off = 8; off > 0; off >>= 1) {
            t[0] += __shfl_xor(t[0], off, 16);
            t[1] += __shfl_xor(t[1], off, 16);
            t[2] += __shfl_xor(t[2], off, 16);
            t[3] += __shfl_xor(t[3], off, 16);
        }
#pragma unroll
        for (int u = 0; u < 4; ++u) {
            float ex = __expf(t[u] * scale);
            den += ex;
            float2 va = H2F(vu[u].x), vb = H2F(vu[u].y);
            num0 = fmaf(ex, va.x, num0);
            num1 = fmaf(ex, va.y, num1);
            num2 = fmaf(ex, vb.x, num2);
            num3 = fmaf(ex, vb.y, num3);
#pragma unroll
            for (int d = 0; d < 8; ++d) sacc[d] = fmaf(ex, a[u][d], sacc[d]);
        }
    }
    for (; j < re; ++j) {
        int s0 = srcp[j];
        float a0[8];
        loadA(eap + (size_t)j * 8, a0);
        uint2 ku0 = *(const uint2*)(K16 + (size_t)s0 * 64 + c0);
        uint2 vu0 = *(const uint2*)(V16 + (size_t)s0 * 64 + c0);
        float2 ka0 = H2F(ku0.x), kb0 = H2F(ku0.y);
        float2 va0 = H2F(vu0.x), vb0 = H2F(vu0.y);
        float t0 = qv.x * ka0.x;
        t0 = fmaf(qv.y, ka0.y, t0); t0 = fmaf(qv.z, kb0.x, t0); t0 = fmaf(qv.w, kb0.y, t0);
#pragma unroll
        for (int d = 0; d < 8; ++d) t0 = fmaf(qe[d], a0[d], t0);
#pragma unroll
        for (int off = 8; off > 0; off >>= 1) t0 += __shfl_xor(t0, off, 16);
        float ex0 = __expf(t0 * scale);
        den += ex0;
        num0 = fmaf(ex0, va0.x, num0);
        num1 = fmaf(ex0, va0.y, num1);
        num2 = fmaf(ex0, vb0.x, num2);
        num3 = fmaf(ex0, vb0.y, num3);
#pragma unroll
        for (int d = 0; d < 8; ++d) sacc[d] = fmaf(ex0, a0[d], sacc[d]);
    }

    // num correction with freshly reloaded we columns
#pragma unroll
    for (int d = 0; d < 8; ++d) {
        float4 w4 = *(const float4*)(we + d * 64 + c0);
        num0 = fmaf(w4.x, sacc[d], num0);
        num1 = fmaf(w4.y, sacc[d], num1);
        num2 = fmaf(w4.z, sacc[d], num2);
        num3 = fmaf(w4.w, sacc[d], num3);
    }
    float inv = 1.f / (den + 1e-16f);
    float o0 = num0 * inv, o1 = num1 * inv, o2 = num2 * inv, o3 = num3 * inv;
    float4 sv  = *(const float4*)(S + (size_t)grp * 64 + c0);
    float4 wb0 = *(const float4*)(wb + c0);
    float4 wb1 = *(const float4*)(wb + 64 + c0);
    float4 wb2 = *(const float4*)(wb + 128 + c0);
    float gd = o0 * wb0.x + sv.x * wb1.x + (o0 - sv.x) * wb2.x;
    gd += o1 * wb0.y + sv.y * wb1.y + (o1 - sv.y) * wb2.y;
    gd += o2 * wb0.z + sv.z * wb1.z + (o2 - sv.z) * wb2.z;
    gd += o3 * wb0.w + sv.w * wb1.w + (o3 - sv.w) * wb2.w;
#pragma unroll
    for (int off = 8; off > 0; off >>= 1) gd += __shfl_xor(gd, off, 16);
    float g = 1.f / (1.f + __expf(-gd));
    float h0 = fmaxf(g * sv.x + (1.f - g) * o0, 0.f);
    float h1 = fmaxf(g * sv.y + (1.f - g) * o1, 0.f);
    float h2 = fmaxf(g * sv.z + (1.f - g) * o2, 0.f);
    float h3 = fmaxf(g * sv.w + (1.f - g) * o3, 0.f);
    float4 wcv = *(const float4*)(wc + c0);
    float t = h0 * wcv.x + h1 * wcv.y + h2 * wcv.z + h3 * wcv.w;
#pragma unroll
    for (int off = 8; off > 0; off >>= 1) t += __shfl_xor(t, off, 16);
    if (l16 == 0) OUT[grp] = t + bc[0];
}

extern "C" void kernel_launch(void* const* d_in, const int* in_sizes, int n_in,
                              void* d_out, int out_size, void* d_ws, size_t ws_size,
                              hipStream_t stream) {
    const float* x  = (const float*)d_in[0];
    const int*   ei = (const int*)d_in[1];
    const float* ea = (const float*)d_in[2];
    const int N = in_sizes[0] / 32;
    const int E = in_sizes[1] / 2;

    int p = 3;
    const float *wq1=(const float*)d_in[p+0], *bq1=(const float*)d_in[p+1],
                *wk1=(const float*)d_in[p+2], *bk1=(const float*)d_in[p+3],
                *wv1=(const float*)d_in[p+4], *bv1=(const float*)d_in[p+5],
                *we1=(const float*)d_in[p+6],
                *wsk1=(const float*)d_in[p+7], *bsk1=(const float*)d_in[p+8],
                *wb1=(const float*)d_in[p+9];
    p += 10;
    const float *wq2=(const float*)d_in[p+0], *bq2=(const float*)d_in[p+1],
                *wk2=(const float*)d_in[p+2], *bk2=(const float*)d_in[p+3],
                *wv2=(const float*)d_in[p+4], *bv2=(const float*)d_in[p+5],
                *we2=(const float*)d_in[p+6],
                *wsk2=(const float*)d_in[p+7], *bsk2=(const float*)d_in[p+8],
                *wb2=(const float*)d_in[p+9];
    p += 10;
    const float *wq3=(const float*)d_in[p+0], *bq3=(const float*)d_in[p+1],
                *wk3=(const float*)d_in[p+2], *bk3=(const float*)d_in[p+3],
                *wv3=(const float*)d_in[p+4], *bv3=(const float*)d_in[p+5],
                *we3=(const float*)d_in[p+6],
                *wsk3=(const float*)d_in[p+7], *bsk3=(const float*)d_in[p+8],
                *wb3=(const float*)d_in[p+9];
    p += 10;
    const float *wc = (const float*)d_in[p+0], *bc = (const float*)d_in[p+1];

    float* out = (float*)d_out;

    // ---- workspace layout ----
    float* ws = (float*)d_ws;
    float* Hb = ws;                               // N*48 fp32
    float* Qb = Hb + (size_t)N * 48;              // N*64 fp32
    float* Sb = Qb + (size_t)N * 64;              // N*64 fp32
    __half* KV16  = (__half*)(Sb + (size_t)N * 64);  // N*128 halfs
    __half* K3    = KV16;
    __half* V3    = KV16 + (size_t)N * 64;
    __half* eap16 = KV16 + (size_t)N * 128;       // E*8 halfs
    int* ip      = (int*)(eap16 + (size_t)E * 8);
    int* rowptr  = ip;                 // N+2
    int* btot    = rowptr + (N + 2);   // 512
    int* bbase   = btot + 512;         // 512
    int* srcp    = bbase + 512;        // E
    int* hist    = srcp + E;           // NBUCK * nblkR
    unsigned* sorted = (unsigned*)Qb;  // aliases Qb; consumed before proj writes

    const int BLK = 256;
    const int nblkR = (E + RCHUNK - 1) / RCHUNK;
    const int nbuckUsed = (N + 255) >> 8;

    // ---------------- radix bucket + LDS counting sort ----------------
    histA_kernel<<<nblkR, 256, 0, stream>>>(ei, hist, E, nblkR);
    scanB_kernel<<<NBUCK, 1024, 0, stream>>>(hist, btot, nblkR);
    scanC_kernel<<<1, NBUCK, 0, stream>>>(btot, bbase);
    reorderB_kernel<<<nblkR, 256, 0, stream>>>(ei, hist, bbase, sorted, E, nblkR);
    bucketsort_kernel<<<nbuckUsed, 256, 0, stream>>>(
        sorted, bbase, btot, rowptr, ei, ea, srcp, eap16, N, E);

    // ------- layer 1: cin=32, H=8, C=6 (PK=16), 2-edge unroll -------
    proj8_kernel<32,6,16><<<(N*48 + BLK-1)/BLK, BLK, 0, stream>>>(
        x, wq1,bq1, wk1,bk1, wv1,bv1, wsk1,bsk1, Qb, KV16, Sb, N);
    gather8f_kernel<6,16,2><<<(N*8 + BLK-1)/BLK, BLK, 0, stream>>>(
        rowptr, srcp, eap16, we1, Qb, KV16, Sb, wb1, Hb, N, 1.0f/sqrtf(6.0f));

    // ------- layer 2: cin=48, H=8, C=3 (PK=8), 4-edge unroll -------
    proj8_kernel<48,3,8><<<(N*24 + BLK-1)/BLK, BLK, 0, stream>>>(
        Hb, wq2,bq2, wk2,bk2, wv2,bv2, wsk2,bsk2, Qb, KV16, Sb, N);
    gather8f_kernel<3,8,4><<<(N*8 + BLK-1)/BLK, BLK, 0, stream>>>(
        rowptr, srcp, eap16, we2, Qb, KV16, Sb, wb2, Hb, N, 1.0f/sqrtf(3.0f));

    // ------- layer 3: cin=24, H=1, C=64, 4-edge unroll -------
    proj64_kernel<<<(N*64 + BLK-1)/BLK, BLK, 0, stream>>>(
        Hb, wq3,bq3, wk3,bk3, wv3,bv3, wsk3,bsk3, Qb, K3, V3, Sb, N);
    gather64f_kernel<<<((size_t)N*16 + BLK-1)/BLK, BLK, 0, stream>>>(
        rowptr, srcp, eap16, we3, Qb, K3, V3, Sb, wb3, wc, bc, out, N, 1.0f/8.0f);
}